// Round 15
// baseline (194.161 us; speedup 1.0000x reference)
//
#include <hip/hip_runtime.h>
#include <hip/hip_bf16.h>

typedef __hip_bfloat16 bf16;
typedef __attribute__((ext_vector_type(8))) short bf16x8;   // 8 bf16 = 4 VGPR (MFMA A/B frag)
typedef __attribute__((ext_vector_type(4))) short bf16x4;   // 4 bf16 = 8B
typedef __attribute__((ext_vector_type(4))) float f32x4;    // MFMA C/D frag

#define TSEQ   2048
#define DMODEL 1024
#define NHEAD  16
#define KST    2112   // padded key count (2049 real, zero-padded), 33*64
#define SCALE  0.17677669529663687f  // 1/sqrt(32) == sem_scale == geo_scale
#define LN1E4_16 0.5756462732485115f // ln(10000)/16

__device__ __forceinline__ unsigned short f2bf(float f) {
    union { bf16 h; unsigned short u; } x;
    x.h = __float2bfloat16(f);
    return x.u;
}
__device__ __forceinline__ float bf2f(unsigned short u) {
    return __uint_as_float(((unsigned int)u) << 16);
}

__device__ __forceinline__ void gload_lds16(const void* g, void* l) {
    __builtin_amdgcn_global_load_lds(
        (const __attribute__((address_space(1))) void*)g,
        (__attribute__((address_space(3))) void*)l, 16, 0, 0);
}

// ---------------------------------------------------------------------------
// prep_all: X convert (bx<2048), 6 weight transposes (bx in [2048,3584)),
// null/pad init + split-K counter zeroing (bx >= 3584).
// ---------------------------------------------------------------------------
__global__ __launch_bounds__(256) void prep_all(
    const float* __restrict__ X,
    const float* __restrict__ wqs, const float* __restrict__ wks,
    const float* __restrict__ wqg, const float* __restrict__ wkg,
    const float* __restrict__ wv,  const float* __restrict__ wo,
    const float* __restrict__ ksn, const float* __restrict__ kgn,
    const float* __restrict__ vn,
    unsigned short* __restrict__ Xb,
    unsigned short* __restrict__ WcatT, unsigned short* __restrict__ WoT,
    unsigned short* __restrict__ Kc, unsigned short* __restrict__ Vg,
    int* __restrict__ cnt)
{
    __shared__ float T[64][65];
    const int bx = blockIdx.x;
    const int tid = threadIdx.x;
    if (bx < 2048) {
        int i = (bx * 256 + tid) * 4;
        float4 v = *(const float4*)(X + i);
        ushort4 o;
        o.x = f2bf(v.x); o.y = f2bf(v.y); o.z = f2bf(v.z); o.w = f2bf(v.w);
        *(ushort4*)(Xb + i) = o;
    } else if (bx < 3584) {
        const int idx = bx - 2048;
        const int z = idx >> 8, rem = idx & 255;
        const int cx = rem & 15, ry = rem >> 4;
        const float* src; unsigned short* dst; int C;
        switch (z) {
            case 0: src = wqs; dst = WcatT;               C = 512;  break;
            case 1: src = wks; dst = WcatT + 512  * 1024; C = 512;  break;
            case 2: src = wqg; dst = WcatT + 1024 * 1024; C = 512;  break;
            case 3: src = wkg; dst = WcatT + 1536 * 1024; C = 512;  break;
            case 4: src = wv;  dst = WcatT + 2048 * 1024; C = 1024; break;
            default: src = wo; dst = WoT;                 C = 1024; break;
        }
        const int c0 = cx * 64;
        if (c0 >= C) return;
        const int r0 = ry * 64;
        #pragma unroll
        for (int i = 0; i < 16; ++i) {
            int id2 = tid + 256 * i;
            int r = id2 >> 6, c = id2 & 63;
            T[r][c] = src[(size_t)(r0 + r) * C + c0 + c];
        }
        __syncthreads();
        #pragma unroll
        for (int i = 0; i < 16; ++i) {
            int id2 = tid + 256 * i;
            int cc = id2 >> 6, rr = id2 & 63;
            dst[(size_t)(c0 + cc) * 1024 + r0 + rr] = f2bf(T[rr][cc]);
        }
    } else {
        const int h = bx - 3584;
        const int d = tid & 63, g = tid >> 6;
        if (tid < 13) cnt[h * 13 + tid] = 0;       // split-K combine counters
        if (g == 0)
            Kc[((size_t)h * KST + 0) * 64 + d] =
                f2bf(d < 32 ? ksn[h * 32 + d] : kgn[h * 32 + d - 32]);
        if (g == 1)
            Vg[((size_t)h * 64 + d) * KST + 0] = f2bf(vn[h * 64 + d]);
        for (int fk = 2049 + g; fk < KST; fk += 4) {
            Kc[((size_t)h * KST + fk) * 64 + d] = 0;
            Vg[((size_t)h * 64 + d) * KST + fk] = 0;
        }
    }
}

// ---------------------------------------------------------------------------
// Fused projection GEMM: 64x128 tile, BK=64, single-buffer swizzled LDS
// (r13-proven). Epilogue writes attention layouts (Qc pre-scaled, RoPE fused).
// ---------------------------------------------------------------------------
__global__ __launch_bounds__(256) void gemm_proj_fused(
    const unsigned short* __restrict__ A,   // Xb [2048][1024]
    const unsigned short* __restrict__ Bt,  // WcatT [3072][1024]
    unsigned short* __restrict__ Qc,
    unsigned short* __restrict__ Kc,
    unsigned short* __restrict__ Vg)
{
    __shared__ __align__(16) unsigned short Abuf[64 * 64];    //  8 KB
    __shared__ __align__(16) unsigned short Bbuf[128 * 64];   // 16 KB
    const int n0 = blockIdx.x * 128, m0 = blockIdx.y * 64;
    const int tid = threadIdx.x, l = tid & 63, wv = tid >> 6;
    const int wr = wv >> 1, wc = wv & 1;      // wave tile: 32 rows x 64 cols
    const int lr = l & 15, lg = l >> 4;

    f32x4 acc[2][4];
    #pragma unroll
    for (int i = 0; i < 2; ++i)
        #pragma unroll
        for (int j = 0; j < 4; ++j) acc[i][j] = (f32x4){0.f, 0.f, 0.f, 0.f};

    for (int k0 = 0; k0 < 1024; k0 += 64) {
        #pragma unroll
        for (int i = 0; i < 2; ++i) {              // A: 2 chunks/thread
            int c = wv * 128 + i * 64 + l;
            int row = c >> 3, sseg = (c & 7) ^ (row & 7);
            gload_lds16(A + (size_t)(m0 + row) * 1024 + k0 + sseg * 8,
                        &Abuf[(wv * 128 + i * 64) * 8]);
        }
        #pragma unroll
        for (int i = 0; i < 4; ++i) {              // B: 4 chunks/thread
            int c = wv * 256 + i * 64 + l;
            int row = c >> 3, sseg = (c & 7) ^ (row & 7);
            gload_lds16(Bt + (size_t)(n0 + row) * 1024 + k0 + sseg * 8,
                        &Bbuf[(wv * 256 + i * 64) * 8]);
        }
        __syncthreads();
        #pragma unroll
        for (int ks = 0; ks < 2; ++ks) {
            bf16x8 af[2], bfv[4];
            #pragma unroll
            for (int mf = 0; mf < 2; ++mf) {
                int rr = wr * 32 + mf * 16 + lr;
                int seg = (ks * 4 + lg) ^ (rr & 7);
                af[mf] = *(const bf16x8*)&Abuf[rr * 64 + seg * 8];
            }
            #pragma unroll
            for (int nf = 0; nf < 4; ++nf) {
                int rr = wc * 64 + nf * 16 + lr;
                int seg = (ks * 4 + lg) ^ (rr & 7);
                bfv[nf] = *(const bf16x8*)&Bbuf[rr * 64 + seg * 8];
            }
            #pragma unroll
            for (int mf = 0; mf < 2; ++mf)
                #pragma unroll
                for (int nf = 0; nf < 4; ++nf)
                    acc[mf][nf] = __builtin_amdgcn_mfma_f32_16x16x32_bf16(
                        af[mf], bfv[nf], acc[mf][nf], 0, 0, 0);
        }
        __syncthreads();
    }

    const int sec = n0 >> 9;   // 0 qs | 1 ks | 2 qg | 3 kg | 4,5 v
    if (sec <= 1) {
        unsigned short* dst = (sec == 0) ? Qc : Kc;
        const int tstr  = (sec == 0) ? TSEQ : KST;
        const int fkoff = (sec == 0) ? 0 : 1;
        const float sc  = (sec == 0) ? SCALE : 1.0f;
        #pragma unroll
        for (int mf = 0; mf < 2; ++mf)
            #pragma unroll
            for (int nf = 0; nf < 4; ++nf) {
                int col = (n0 & 511) + wc * 64 + nf * 16 + lr;
                int h = col >> 5, d = col & 31;
                #pragma unroll
                for (int reg = 0; reg < 4; ++reg) {
                    int q = m0 + wr * 32 + mf * 16 + lg * 4 + reg;
                    dst[((size_t)h * tstr + q + fkoff) * 64 + d] =
                        f2bf(acc[mf][nf][reg] * sc);
                }
            }
    } else if (sec <= 3) {
        unsigned short* dst = (sec == 2) ? Qc : Kc;
        const int tstr  = (sec == 2) ? TSEQ : KST;
        const int fkoff = (sec == 2) ? 0 : 1;
        const float sc  = (sec == 2) ? SCALE : 1.0f;
        const float invf = __expf(-(float)lr * LN1E4_16);
        #pragma unroll
        for (int mf = 0; mf < 2; ++mf)
            #pragma unroll
            for (int reg = 0; reg < 4; ++reg) {
                int q = m0 + wr * 32 + mf * 16 + lg * 4 + reg;
                float s, c;
                __sincosf((float)q * invf, &s, &c);
                #pragma unroll
                for (int nfp = 0; nfp < 2; ++nfp) {
                    int nf0 = nfp * 2;
                    int colbase = (n0 & 511) + wc * 64 + nf0 * 16;
                    int h = colbase >> 5;
                    float x1 = acc[mf][nf0][reg], x2 = acc[mf][nf0 + 1][reg];
                    size_t base = ((size_t)h * tstr + q + fkoff) * 64 + 32;
                    dst[base + lr]      = f2bf((x1 * c - x2 * s) * sc);
                    dst[base + lr + 16] = f2bf((x2 * c + x1 * s) * sc);
                }
            }
    } else {
        #pragma unroll
        for (int nf = 0; nf < 4; ++nf) {
            int colr = (n0 - 2048) + wc * 64 + nf * 16 + lr;
            int h = colr >> 6, dv = colr & 63;
            size_t rowbase = ((size_t)h * 64 + dv) * KST;
            #pragma unroll
            for (int mf = 0; mf < 2; ++mf)
                #pragma unroll
                for (int reg = 0; reg < 4; ++reg) {
                    int q = m0 + wr * 32 + mf * 16 + lg * 4 + reg;
                    Vg[rowbase + q + 1] = f2bf(acc[mf][nf][reg]);
                }
        }
    }
}

// ---------------------------------------------------------------------------
// Output GEMM: 64x128 tile, BK=64, single-buffer swizzled LDS (r13-proven).
// ---------------------------------------------------------------------------
__global__ __launch_bounds__(256) void gemm_out(const unsigned short* __restrict__ A,
                                                const unsigned short* __restrict__ Bt,
                                                float* __restrict__ C)
{
    __shared__ __align__(16) unsigned short Abuf[64 * 64];
    __shared__ __align__(16) unsigned short Bbuf[128 * 64];
    const int n0 = blockIdx.x * 128, m0 = blockIdx.y * 64;
    const int tid = threadIdx.x, l = tid & 63, wv = tid >> 6;
    const int wr = wv >> 1, wc = wv & 1;
    const int lr = l & 15, lg = l >> 4;

    f32x4 acc[2][4];
    #pragma unroll
    for (int i = 0; i < 2; ++i)
        #pragma unroll
        for (int j = 0; j < 4; ++j) acc[i][j] = (f32x4){0.f, 0.f, 0.f, 0.f};

    for (int k0 = 0; k0 < 1024; k0 += 64) {
        #pragma unroll
        for (int i = 0; i < 2; ++i) {
            int c = wv * 128 + i * 64 + l;
            int row = c >> 3, sseg = (c & 7) ^ (row & 7);
            gload_lds16(A + (size_t)(m0 + row) * 1024 + k0 + sseg * 8,
                        &Abuf[(wv * 128 + i * 64) * 8]);
        }
        #pragma unroll
        for (int i = 0; i < 4; ++i) {
            int c = wv * 256 + i * 64 + l;
            int row = c >> 3, sseg = (c & 7) ^ (row & 7);
            gload_lds16(Bt + (size_t)(n0 + row) * 1024 + k0 + sseg * 8,
                        &Bbuf[(wv * 256 + i * 64) * 8]);
        }
        __syncthreads();
        #pragma unroll
        for (int ks = 0; ks < 2; ++ks) {
            bf16x8 af[2], bfv[4];
            #pragma unroll
            for (int mf = 0; mf < 2; ++mf) {
                int rr = wr * 32 + mf * 16 + lr;
                int seg = (ks * 4 + lg) ^ (rr & 7);
                af[mf] = *(const bf16x8*)&Abuf[rr * 64 + seg * 8];
            }
            #pragma unroll
            for (int nf = 0; nf < 4; ++nf) {
                int rr = wc * 64 + nf * 16 + lr;
                int seg = (ks * 4 + lg) ^ (rr & 7);
                bfv[nf] = *(const bf16x8*)&Bbuf[rr * 64 + seg * 8];
            }
            #pragma unroll
            for (int mf = 0; mf < 2; ++mf)
                #pragma unroll
                for (int nf = 0; nf < 4; ++nf)
                    acc[mf][nf] = __builtin_amdgcn_mfma_f32_16x16x32_bf16(
                        af[mf], bfv[nf], acc[mf][nf], 0, 0, 0);
        }
        __syncthreads();
    }
    #pragma unroll
    for (int mf = 0; mf < 2; ++mf)
        #pragma unroll
        for (int nf = 0; nf < 4; ++nf)
            #pragma unroll
            for (int reg = 0; reg < 4; ++reg) {
                int row = m0 + wr * 32 + mf * 16 + lg * 4 + reg;
                int col = n0 + wc * 64 + nf * 16 + lr;
                C[(size_t)row * DMODEL + col] = acc[mf][nf][reg];
            }
}

// ---------------------------------------------------------------------------
// MFMA flash attention, QBLK=128, depth-2 pipeline (r13-proven) + FUSED
// split-K combine: last-finishing part of each (h,qb) group combines the
// partials in-kernel (device-scope atomic counter + threadfence protocol).
// ---------------------------------------------------------------------------
__global__ __launch_bounds__(256, 3) void attn_mfma(
    const unsigned short* __restrict__ Qc,
    const unsigned short* __restrict__ Kc,
    const unsigned short* __restrict__ Vg,
    unsigned short* __restrict__ attnO,
    unsigned short* __restrict__ OpA,
    unsigned short* __restrict__ OpB,
    float2* __restrict__ ml,
    int* __restrict__ cnt)
{
    __shared__ __align__(16) unsigned short KsL[3][64 * 64];   // 24 KB
    __shared__ __align__(16) unsigned short VsL[2][64 * 64];   // 16 KB
    __shared__ __align__(16) unsigned short Ps[64 * 64];       //  8 KB
    __shared__ int go;

    const int ib = blockIdx.x;          // 0..655
    const int hp = ib & 7;
    const int j  = ib >> 3;             // 0..81
    const int h  = hp * 2 + (j & 1);
    const int item = j >> 1;            // 0..40, heavy-first

    int qb, part, np;
    {
        int i = item;
        if (i < 16)      { np = 4; qb = 15 - (i >> 2); part = i & 3; }
        else if (i < 28) { int jj = i - 16; np = 3; qb = 11 - jj / 3; part = jj % 3; }
        else if (i < 38) { int jj = i - 28; np = 2; qb = 7 - (jj >> 1); part = jj & 1; }
        else             { np = 1; qb = 2 - (i - 38); part = 0; }
    }
    const int nt = 2 * qb + 3;
    const int bsz = nt / np, rem = nt % np;
    const int t0 = part * bsz + (part < rem ? part : rem);
    const int t1 = t0 + bsz + (part < rem ? 1 : 0);   // t1-t0 >= 3 always

    const int q0 = qb * 128;
    const int tid = threadIdx.x, l = tid & 63, w = tid >> 6;
    const int lr = l & 15, lg = l >> 4;

    bf16x8 qa[2][2];
    #pragma unroll
    for (int rg = 0; rg < 2; ++rg) {
        int qr = q0 + w * 32 + rg * 16 + lr;
        qa[rg][0] = *(const bf16x8*)&Qc[((size_t)h * TSEQ + qr) * 64 + lg * 8];
        qa[rg][1] = *(const bf16x8*)&Qc[((size_t)h * TSEQ + qr) * 64 + 32 + lg * 8];
    }

    const int sc8 = (((l & 7) ^ ((l >> 3) & 7))) * 8;
    const int r0s = (w * 2 + 0) * 8 + (l >> 3);
    const int r1s = (w * 2 + 1) * 8 + (l >> 3);
    const unsigned short* Kh = Kc + (((size_t)h * KST) << 6);
    const unsigned short* Vh = Vg + (size_t)h * 64 * KST;

#define STAGE_K(bufi, fk0_) do {                                               \
        gload_lds16(Kh + (((size_t)((fk0_) + r0s)) << 6) + sc8,                \
                    &KsL[bufi][(w * 2 + 0) * 512]);                            \
        gload_lds16(Kh + (((size_t)((fk0_) + r1s)) << 6) + sc8,                \
                    &KsL[bufi][(w * 2 + 1) * 512]);                            \
    } while (0)
#define STAGE_V(bufi, fk0_) do {                                               \
        gload_lds16(Vh + (size_t)r0s * KST + (fk0_) + sc8,                     \
                    &VsL[bufi][(w * 2 + 0) * 512]);                            \
        gload_lds16(Vh + (size_t)r1s * KST + (fk0_) + sc8,                     \
                    &VsL[bufi][(w * 2 + 1) * 512]);                            \
    } while (0)

    f32x4 o[2][4];
    #pragma unroll
    for (int rg = 0; rg < 2; ++rg)
        #pragma unroll
        for (int i = 0; i < 4; ++i) o[rg][i] = (f32x4){0.f, 0.f, 0.f, 0.f};
    float m[2]  = {-1e30f, -1e30f};
    float ll[2] = {0.f, 0.f};

    STAGE_K(t0 % 3, t0 * 64);
    STAGE_V(t0 & 1, t0 * 64);
    STAGE_K((t0 + 1) % 3, (t0 + 1) * 64);
    asm volatile("s_waitcnt vmcnt(2)" ::: "memory");
    __builtin_amdgcn_s_barrier();

    for (int kb = t0; kb < t1; ++kb) {
        const int fk0 = kb * 64;
        const unsigned short* Ksb = &KsL[kb % 3][0];
        const unsigned short* Vsb = &VsL[kb & 1][0];
        const bool moreV = (kb + 1 < t1);
        const bool moreK = (kb + 2 < t1);
        if (moreV) STAGE_V((kb + 1) & 1, fk0 + 64);    // V first (drained at bottom)
        if (moreK) STAGE_K((kb + 2) % 3, fk0 + 128);   // K second (stays in flight)

        bf16x8 vb[2][4];
        #pragma unroll
        for (int ks = 0; ks < 2; ++ks)
            #pragma unroll
            for (int nf = 0; nf < 4; ++nf) {
                int dv = nf * 16 + lr;
                vb[ks][nf] = *(const bf16x8*)
                    &Vsb[dv * 64 + ((lg * 8 + ks * 32) ^ ((dv & 7) << 3))];
            }

        f32x4 sa[2][4];
        #pragma unroll
        for (int rg = 0; rg < 2; ++rg)
            #pragma unroll
            for (int i = 0; i < 4; ++i) sa[rg][i] = (f32x4){0.f, 0.f, 0.f, 0.f};
        #pragma unroll
        for (int ks = 0; ks < 2; ++ks) {
            int dd = lg * 8 + ks * 32;
            #pragma unroll
            for (int nf = 0; nf < 4; ++nf) {
                int kkc = nf * 16 + lr;
                bf16x8 kbf = *(const bf16x8*)&Ksb[kkc * 64 + (dd ^ ((kkc & 7) << 3))];
                sa[0][nf] = __builtin_amdgcn_mfma_f32_16x16x32_bf16(kbf, qa[0][ks], sa[0][nf], 0, 0, 0);
                sa[1][nf] = __builtin_amdgcn_mfma_f32_16x16x32_bf16(kbf, qa[1][ks], sa[1][nf], 0, 0, 0);
            }
        }

        const bool needmask = (fk0 + 62 > q0 + w * 32);
        const int pr = w * 16 + lr;
        const int psw = (pr & 7) << 3;
        #pragma unroll
        for (int rg = 0; rg < 2; ++rg) {
            const int q = q0 + w * 32 + rg * 16 + lr;
            float mt = -1e30f;
            if (needmask) {
                #pragma unroll
                for (int nf = 0; nf < 4; ++nf)
                    #pragma unroll
                    for (int reg = 0; reg < 4; ++reg) {
                        int fk = fk0 + nf * 16 + lg * 4 + reg;
                        float val = (fk <= q + 1) ? sa[rg][nf][reg] : -1e9f;
                        sa[rg][nf][reg] = val;
                        mt = fmaxf(mt, val);
                    }
            } else {
                #pragma unroll
                for (int nf = 0; nf < 4; ++nf)
                    #pragma unroll
                    for (int reg = 0; reg < 4; ++reg)
                        mt = fmaxf(mt, sa[rg][nf][reg]);
            }
            mt = fmaxf(mt, __shfl_xor(mt, 16, 64));
            mt = fmaxf(mt, __shfl_xor(mt, 32, 64));
            if (__any(mt > m[rg] + 8.0f)) {       // T13 defer-max
                float mn = fmaxf(m[rg], mt);
                float alpha = __expf(m[rg] - mn);
                m[rg] = mn;
                ll[rg] *= alpha;
                #pragma unroll
                for (int nf = 0; nf < 4; ++nf)
                    #pragma unroll
                    for (int reg = 0; reg < 4; ++reg)
                        o[rg][nf][reg] *= alpha;
            }
            float rs = 0.0f;
            #pragma unroll
            for (int nf = 0; nf < 4; ++nf)
                #pragma unroll
                for (int reg = 0; reg < 4; ++reg) {
                    float p = __expf(sa[rg][nf][reg] - m[rg]);
                    sa[rg][nf][reg] = p;
                    rs += p;
                }
            rs += __shfl_xor(rs, 16, 64);
            rs += __shfl_xor(rs, 32, 64);
            ll[rg] += rs;

            #pragma unroll
            for (int nf = 0; nf < 4; ++nf) {
                bf16x4 pk;
                pk[0] = f2bf(sa[rg][nf][0]); pk[1] = f2bf(sa[rg][nf][1]);
                pk[2] = f2bf(sa[rg][nf][2]); pk[3] = f2bf(sa[rg][nf][3]);
                int kk0 = nf * 16 + lg * 4;
                *(bf16x4*)&Ps[pr * 64 + (kk0 ^ psw)] = pk;
            }
            #pragma unroll
            for (int ks = 0; ks < 2; ++ks) {
                int kk0 = lg * 8 + ks * 32;
                bf16x8 pa = *(const bf16x8*)&Ps[pr * 64 + (kk0 ^ psw)];
                #pragma unroll
                for (int nf = 0; nf < 4; ++nf)
                    o[rg][nf] = __builtin_amdgcn_mfma_f32_16x16x32_bf16(
                        vb[ks][nf], pa, o[rg][nf], 0, 0, 0);
            }
        }

        if (moreK) { asm volatile("s_waitcnt vmcnt(2)" ::: "memory"); }
        else       { asm volatile("s_waitcnt vmcnt(0)" ::: "memory"); }
        __builtin_amdgcn_s_barrier();
    }
#undef STAGE_K
#undef STAGE_V

    const int sidx = h * 38 + item;
    unsigned short* Od = (np == 1) ? 0
        : ((sidx < 384) ? OpA + (size_t)sidx * 8192
                        : OpB + (size_t)(sidx - 384) * 8192);
    #pragma unroll
    for (int rg = 0; rg < 2; ++rg) {
        const float inv = 1.0f / ll[rg];
        const int q = q0 + w * 32 + rg * 16 + lr;
        if (np == 1) {
            #pragma unroll
            for (int nf = 0; nf < 4; ++nf) {
                ushort4 ov;
                ov.x = f2bf(o[rg][nf][0] * inv); ov.y = f2bf(o[rg][nf][1] * inv);
                ov.z = f2bf(o[rg][nf][2] * inv); ov.w = f2bf(o[rg][nf][3] * inv);
                *(ushort4*)&attnO[(size_t)q * DMODEL + h * 64 + nf * 16 + lg * 4] = ov;
            }
        } else {
            const int r = w * 32 + rg * 16 + lr;
            #pragma unroll
            for (int nf = 0; nf < 4; ++nf) {
                ushort4 ov;
                ov.x = f2bf(o[rg][nf][0] * inv); ov.y = f2bf(o[rg][nf][1] * inv);
                ov.z = f2bf(o[rg][nf][2] * inv); ov.w = f2bf(o[rg][nf][3] * inv);
                *(ushort4*)&Od[r * 64 + nf * 16 + lg * 4] = ov;
            }
            if (lg == 0)
                ml[sidx * 128 + r] = make_float2(m[rg], ll[rg]);
        }
    }

    // ---- fused combine: last-arriving part of this (h,qb) group combines.
    if (np > 1) {
        __threadfence();            // publish this block's Od/ml device-wide
        __syncthreads();
        if (tid == 0) {
            int prev = atomicAdd(&cnt[h * 13 + (qb - 3)], 1);
            go = (prev == np - 1) ? 1 : 0;
        }
        __syncthreads();
        if (go) {
            __threadfence();        // acquire: see other parts' writes
            int i0;
            if (qb >= 12)     i0 = (15 - qb) * 4;
            else if (qb >= 8) i0 = 16 + (11 - qb) * 3;
            else              i0 = 28 + (7 - qb) * 2;
            const int sidx0 = h * 38 + i0;
            const int r = tid & 127, dv0 = (tid >> 7) * 32;

            float wt[4];
            float mm = -1e30f;
            #pragma unroll
            for (int p = 0; p < 4; ++p)
                if (p < np) mm = fmaxf(mm, ml[(sidx0 + p) * 128 + r].x);
            float tot = 0.0f;
            #pragma unroll
            for (int p = 0; p < 4; ++p) {
                wt[p] = 0.0f;
                if (p < np) {
                    float2 v = ml[(sidx0 + p) * 128 + r];
                    wt[p] = v.y * __expf(v.x - mm);
                    tot += wt[p];
                }
            }
            const float inv = 1.0f / tot;

            float accv[32];
            #pragma unroll
            for (int c = 0; c < 32; ++c) accv[c] = 0.0f;
            #pragma unroll
            for (int p = 0; p < 4; ++p) {
                if (p < np) {
                    int s = sidx0 + p;
                    const unsigned short* Op = (s < 384)
                        ? OpA + (size_t)s * 8192
                        : OpB + (size_t)(s - 384) * 8192;
                    #pragma unroll
                    for (int c4 = 0; c4 < 8; ++c4) {
                        ushort4 v = *(const ushort4*)&Op[r * 64 + dv0 + c4 * 4];
                        accv[c4 * 4 + 0] += wt[p] * bf2f(v.x);
                        accv[c4 * 4 + 1] += wt[p] * bf2f(v.y);
                        accv[c4 * 4 + 2] += wt[p] * bf2f(v.z);
                        accv[c4 * 4 + 3] += wt[p] * bf2f(v.w);
                    }
                }
            }
            const int qq = qb * 128 + r;
            #pragma unroll
            for (int c4 = 0; c4 < 8; ++c4) {
                ushort4 ov;
                ov.x = f2bf(accv[c4 * 4 + 0] * inv);
                ov.y = f2bf(accv[c4 * 4 + 1] * inv);
                ov.z = f2bf(accv[c4 * 4 + 2] * inv);
                ov.w = f2bf(accv[c4 * 4 + 3] * inv);
                *(ushort4*)&attnO[(size_t)qq * DMODEL + h * 64 + dv0 + c4 * 4] = ov;
            }
        }
    }
}

// ---------------------------------------------------------------------------
extern "C" void kernel_launch(void* const* d_in, const int* in_sizes, int n_in,
                              void* d_out, int out_size, void* d_ws, size_t ws_size,
                              hipStream_t stream)
{
    const float* x      = (const float*)d_in[0];
    const float* wq_sem = (const float*)d_in[1];
    const float* wk_sem = (const float*)d_in[2];
    const float* wq_geo = (const float*)d_in[3];
    const float* wk_geo = (const float*)d_in[4];
    const float* wv     = (const float*)d_in[5];
    const float* wo     = (const float*)d_in[6];
    const float* ksn    = (const float*)d_in[7];
    const float* kgn    = (const float*)d_in[8];
    const float* vn     = (const float*)d_in[9];
    float* out = (float*)d_out;

    // Workspace (peak 29.73 MiB):
    //  [0,        4.19M)  Xb -> attnO
    //  [4.19M,   10.49M)  WcatT -> OpA (384 partials x 16KB)
    //  [10.49M,  12.58M)  WoT
    //  [12.58M,  16.78M)  Qc  [16][2048][64]
    //  [16.78M,  21.10M)  Kc  [16][2112][64]
    //  [21.10M,  25.43M)  Vg  [16][64][2112]
    //  [25.43M,  29.10M)  OpB (224 partials x 16KB)
    //  [29.10M,  29.72M)  ml  float2 [608][128]
    //  [29.72M, +832B)    cnt int [16*13]
    char* ws = (char*)d_ws;
    unsigned short* Xb    = (unsigned short*)(ws);
    unsigned short* attnO = (unsigned short*)(ws);
    unsigned short* WcatT = (unsigned short*)(ws + 4194304);
    unsigned short* OpA   = (unsigned short*)(ws + 4194304);
    unsigned short* WoT   = (unsigned short*)(ws + 10485760);
    unsigned short* Qc    = (unsigned short*)(ws + 12582912);
    unsigned short* Kc    = (unsigned short*)(ws + 16777216);
    unsigned short* Vg    = (unsigned short*)(ws + 21102592);
    unsigned short* OpB   = (unsigned short*)(ws + 25427968);
    float2*         ml    = (float2*)(ws + 29097984);
    int*            cnt   = (int*)(ws + 29720576);

    prep_all<<<3600, 256, 0, stream>>>(x, wq_sem, wk_sem, wq_geo, wk_geo, wv, wo,
                                       ksn, kgn, vn, Xb, WcatT, WoT, Kc, Vg, cnt);

    gemm_proj_fused<<<dim3(24, 32), 256, 0, stream>>>(Xb, WcatT, Qc, Kc, Vg);

    attn_mfma<<<656, 256, 0, stream>>>(Qc, Kc, Vg, attnO, OpA, OpB, ml, cnt);

    gemm_out<<<dim3(8, 32), 256, 0, stream>>>(attnO, WoT, out);
}

// Round 16
// 83.933 us; speedup vs baseline: 2.3133x; 2.3133x over previous
//
#include <hip/hip_runtime.h>
#include <hip/hip_bf16.h>

typedef __hip_bfloat16 bf16;
typedef __attribute__((ext_vector_type(8))) short bf16x8;   // 8 bf16 = 4 VGPR (MFMA A/B frag)
typedef __attribute__((ext_vector_type(4))) short bf16x4;   // 4 bf16 = 8B
typedef __attribute__((ext_vector_type(4))) float f32x4;    // MFMA C/D frag

#define TSEQ   2048
#define DMODEL 1024
#define NHEAD  16
#define KST    2112   // padded key count (2049 real, zero-padded), 33*64
#define SCALE  0.17677669529663687f  // 1/sqrt(32) == sem_scale == geo_scale
#define LN1E4_16 0.5756462732485115f // ln(10000)/16

__device__ __forceinline__ unsigned short f2bf(float f) {
    union { bf16 h; unsigned short u; } x;
    x.h = __float2bfloat16(f);
    return x.u;
}
__device__ __forceinline__ float bf2f(unsigned short u) {
    return __uint_as_float(((unsigned int)u) << 16);
}

__device__ __forceinline__ void gload_lds16(const void* g, void* l) {
    __builtin_amdgcn_global_load_lds(
        (const __attribute__((address_space(1))) void*)g,
        (__attribute__((address_space(3))) void*)l, 16, 0, 0);
}

// ---------------------------------------------------------------------------
// prep_all: one launch for X convert (bx<2048), 6 weight transposes
// (bx in [2048,3584)), and null/pad init (bx >= 3584).
// ---------------------------------------------------------------------------
__global__ __launch_bounds__(256) void prep_all(
    const float* __restrict__ X,
    const float* __restrict__ wqs, const float* __restrict__ wks,
    const float* __restrict__ wqg, const float* __restrict__ wkg,
    const float* __restrict__ wv,  const float* __restrict__ wo,
    const float* __restrict__ ksn, const float* __restrict__ kgn,
    const float* __restrict__ vn,
    unsigned short* __restrict__ Xb,
    unsigned short* __restrict__ WcatT, unsigned short* __restrict__ WoT,
    unsigned short* __restrict__ Kc, unsigned short* __restrict__ Vg)
{
    __shared__ float T[64][65];
    const int bx = blockIdx.x;
    const int tid = threadIdx.x;
    if (bx < 2048) {
        int i = (bx * 256 + tid) * 4;
        float4 v = *(const float4*)(X + i);
        ushort4 o;
        o.x = f2bf(v.x); o.y = f2bf(v.y); o.z = f2bf(v.z); o.w = f2bf(v.w);
        *(ushort4*)(Xb + i) = o;
    } else if (bx < 3584) {
        const int idx = bx - 2048;
        const int z = idx >> 8, rem = idx & 255;
        const int cx = rem & 15, ry = rem >> 4;
        const float* src; unsigned short* dst; int C;
        switch (z) {
            case 0: src = wqs; dst = WcatT;               C = 512;  break;
            case 1: src = wks; dst = WcatT + 512  * 1024; C = 512;  break;
            case 2: src = wqg; dst = WcatT + 1024 * 1024; C = 512;  break;
            case 3: src = wkg; dst = WcatT + 1536 * 1024; C = 512;  break;
            case 4: src = wv;  dst = WcatT + 2048 * 1024; C = 1024; break;
            default: src = wo; dst = WoT;                 C = 1024; break;
        }
        const int c0 = cx * 64;
        if (c0 >= C) return;
        const int r0 = ry * 64;
        #pragma unroll
        for (int i = 0; i < 16; ++i) {
            int id2 = tid + 256 * i;
            int r = id2 >> 6, c = id2 & 63;
            T[r][c] = src[(size_t)(r0 + r) * C + c0 + c];
        }
        __syncthreads();
        #pragma unroll
        for (int i = 0; i < 16; ++i) {
            int id2 = tid + 256 * i;
            int cc = id2 >> 6, rr = id2 & 63;
            dst[(size_t)(c0 + cc) * 1024 + r0 + rr] = f2bf(T[rr][cc]);
        }
    } else {
        const int h = bx - 3584;
        const int d = tid & 63, g = tid >> 6;
        if (g == 0)
            Kc[((size_t)h * KST + 0) * 64 + d] =
                f2bf(d < 32 ? ksn[h * 32 + d] : kgn[h * 32 + d - 32]);
        if (g == 1)
            Vg[((size_t)h * 64 + d) * KST + 0] = f2bf(vn[h * 64 + d]);
        for (int fk = 2049 + g; fk < KST; fk += 4) {
            Kc[((size_t)h * KST + fk) * 64 + d] = 0;
            Vg[((size_t)h * 64 + d) * KST + fk] = 0;
        }
    }
}

// ---------------------------------------------------------------------------
// Fused projection GEMM: 64x128 tile, BK=64, single-buffer swizzled LDS.
// Epilogue writes attention layouts (Qc pre-scaled, RoPE fused).
// ---------------------------------------------------------------------------
__global__ __launch_bounds__(256) void gemm_proj_fused(
    const unsigned short* __restrict__ A,   // Xb [2048][1024]
    const unsigned short* __restrict__ Bt,  // WcatT [3072][1024]
    unsigned short* __restrict__ Qc,
    unsigned short* __restrict__ Kc,
    unsigned short* __restrict__ Vg)
{
    __shared__ __align__(16) unsigned short Abuf[64 * 64];    //  8 KB
    __shared__ __align__(16) unsigned short Bbuf[128 * 64];   // 16 KB
    const int n0 = blockIdx.x * 128, m0 = blockIdx.y * 64;
    const int tid = threadIdx.x, l = tid & 63, wv = tid >> 6;
    const int wr = wv >> 1, wc = wv & 1;      // wave tile: 32 rows x 64 cols
    const int lr = l & 15, lg = l >> 4;

    f32x4 acc[2][4];
    #pragma unroll
    for (int i = 0; i < 2; ++i)
        #pragma unroll
        for (int j = 0; j < 4; ++j) acc[i][j] = (f32x4){0.f, 0.f, 0.f, 0.f};

    for (int k0 = 0; k0 < 1024; k0 += 64) {
        #pragma unroll
        for (int i = 0; i < 2; ++i) {              // A: 2 chunks/thread
            int c = wv * 128 + i * 64 + l;
            int row = c >> 3, sseg = (c & 7) ^ (row & 7);
            gload_lds16(A + (size_t)(m0 + row) * 1024 + k0 + sseg * 8,
                        &Abuf[(wv * 128 + i * 64) * 8]);
        }
        #pragma unroll
        for (int i = 0; i < 4; ++i) {              // B: 4 chunks/thread
            int c = wv * 256 + i * 64 + l;
            int row = c >> 3, sseg = (c & 7) ^ (row & 7);
            gload_lds16(Bt + (size_t)(n0 + row) * 1024 + k0 + sseg * 8,
                        &Bbuf[(wv * 256 + i * 64) * 8]);
        }
        __syncthreads();
        #pragma unroll
        for (int ks = 0; ks < 2; ++ks) {
            bf16x8 af[2], bfv[4];
            #pragma unroll
            for (int mf = 0; mf < 2; ++mf) {
                int rr = wr * 32 + mf * 16 + lr;
                int seg = (ks * 4 + lg) ^ (rr & 7);
                af[mf] = *(const bf16x8*)&Abuf[rr * 64 + seg * 8];
            }
            #pragma unroll
            for (int nf = 0; nf < 4; ++nf) {
                int rr = wc * 64 + nf * 16 + lr;
                int seg = (ks * 4 + lg) ^ (rr & 7);
                bfv[nf] = *(const bf16x8*)&Bbuf[rr * 64 + seg * 8];
            }
            #pragma unroll
            for (int mf = 0; mf < 2; ++mf)
                #pragma unroll
                for (int nf = 0; nf < 4; ++nf)
                    acc[mf][nf] = __builtin_amdgcn_mfma_f32_16x16x32_bf16(
                        af[mf], bfv[nf], acc[mf][nf], 0, 0, 0);
        }
        __syncthreads();
    }

    const int sec = n0 >> 9;   // 0 qs | 1 ks | 2 qg | 3 kg | 4,5 v
    if (sec <= 1) {
        unsigned short* dst = (sec == 0) ? Qc : Kc;
        const int tstr  = (sec == 0) ? TSEQ : KST;
        const int fkoff = (sec == 0) ? 0 : 1;
        const float sc  = (sec == 0) ? SCALE : 1.0f;
        #pragma unroll
        for (int mf = 0; mf < 2; ++mf)
            #pragma unroll
            for (int nf = 0; nf < 4; ++nf) {
                int col = (n0 & 511) + wc * 64 + nf * 16 + lr;
                int h = col >> 5, d = col & 31;
                #pragma unroll
                for (int reg = 0; reg < 4; ++reg) {
                    int q = m0 + wr * 32 + mf * 16 + lg * 4 + reg;
                    dst[((size_t)h * tstr + q + fkoff) * 64 + d] =
                        f2bf(acc[mf][nf][reg] * sc);
                }
            }
    } else if (sec <= 3) {
        unsigned short* dst = (sec == 2) ? Qc : Kc;
        const int tstr  = (sec == 2) ? TSEQ : KST;
        const int fkoff = (sec == 2) ? 0 : 1;
        const float sc  = (sec == 2) ? SCALE : 1.0f;
        const float invf = __expf(-(float)lr * LN1E4_16);
        #pragma unroll
        for (int mf = 0; mf < 2; ++mf)
            #pragma unroll
            for (int reg = 0; reg < 4; ++reg) {
                int q = m0 + wr * 32 + mf * 16 + lg * 4 + reg;
                float s, c;
                __sincosf((float)q * invf, &s, &c);
                #pragma unroll
                for (int nfp = 0; nfp < 2; ++nfp) {
                    int nf0 = nfp * 2;
                    int colbase = (n0 & 511) + wc * 64 + nf0 * 16;
                    int h = colbase >> 5;
                    float x1 = acc[mf][nf0][reg], x2 = acc[mf][nf0 + 1][reg];
                    size_t base = ((size_t)h * tstr + q + fkoff) * 64 + 32;
                    dst[base + lr]      = f2bf((x1 * c - x2 * s) * sc);
                    dst[base + lr + 16] = f2bf((x2 * c + x1 * s) * sc);
                }
            }
    } else {
        #pragma unroll
        for (int nf = 0; nf < 4; ++nf) {
            int colr = (n0 - 2048) + wc * 64 + nf * 16 + lr;
            int h = colr >> 6, dv = colr & 63;
            size_t rowbase = ((size_t)h * 64 + dv) * KST;
            #pragma unroll
            for (int mf = 0; mf < 2; ++mf)
                #pragma unroll
                for (int reg = 0; reg < 4; ++reg) {
                    int q = m0 + wr * 32 + mf * 16 + lg * 4 + reg;
                    Vg[rowbase + q + 1] = f2bf(acc[mf][nf][reg]);
                }
        }
    }
}

// ---------------------------------------------------------------------------
// Output GEMM: 64x128 tile, BK=64, single-buffer swizzled LDS.
// ---------------------------------------------------------------------------
__global__ __launch_bounds__(256) void gemm_out(const unsigned short* __restrict__ A,
                                                const unsigned short* __restrict__ Bt,
                                                float* __restrict__ C)
{
    __shared__ __align__(16) unsigned short Abuf[64 * 64];
    __shared__ __align__(16) unsigned short Bbuf[128 * 64];
    const int n0 = blockIdx.x * 128, m0 = blockIdx.y * 64;
    const int tid = threadIdx.x, l = tid & 63, wv = tid >> 6;
    const int wr = wv >> 1, wc = wv & 1;
    const int lr = l & 15, lg = l >> 4;

    f32x4 acc[2][4];
    #pragma unroll
    for (int i = 0; i < 2; ++i)
        #pragma unroll
        for (int j = 0; j < 4; ++j) acc[i][j] = (f32x4){0.f, 0.f, 0.f, 0.f};

    for (int k0 = 0; k0 < 1024; k0 += 64) {
        #pragma unroll
        for (int i = 0; i < 2; ++i) {
            int c = wv * 128 + i * 64 + l;
            int row = c >> 3, sseg = (c & 7) ^ (row & 7);
            gload_lds16(A + (size_t)(m0 + row) * 1024 + k0 + sseg * 8,
                        &Abuf[(wv * 128 + i * 64) * 8]);
        }
        #pragma unroll
        for (int i = 0; i < 4; ++i) {
            int c = wv * 256 + i * 64 + l;
            int row = c >> 3, sseg = (c & 7) ^ (row & 7);
            gload_lds16(Bt + (size_t)(n0 + row) * 1024 + k0 + sseg * 8,
                        &Bbuf[(wv * 256 + i * 64) * 8]);
        }
        __syncthreads();
        #pragma unroll
        for (int ks = 0; ks < 2; ++ks) {
            bf16x8 af[2], bfv[4];
            #pragma unroll
            for (int mf = 0; mf < 2; ++mf) {
                int rr = wr * 32 + mf * 16 + lr;
                int seg = (ks * 4 + lg) ^ (rr & 7);
                af[mf] = *(const bf16x8*)&Abuf[rr * 64 + seg * 8];
            }
            #pragma unroll
            for (int nf = 0; nf < 4; ++nf) {
                int rr = wc * 64 + nf * 16 + lr;
                int seg = (ks * 4 + lg) ^ (rr & 7);
                bfv[nf] = *(const bf16x8*)&Bbuf[rr * 64 + seg * 8];
            }
            #pragma unroll
            for (int mf = 0; mf < 2; ++mf)
                #pragma unroll
                for (int nf = 0; nf < 4; ++nf)
                    acc[mf][nf] = __builtin_amdgcn_mfma_f32_16x16x32_bf16(
                        af[mf], bfv[nf], acc[mf][nf], 0, 0, 0);
        }
        __syncthreads();
    }
    #pragma unroll
    for (int mf = 0; mf < 2; ++mf)
        #pragma unroll
        for (int nf = 0; nf < 4; ++nf)
            #pragma unroll
            for (int reg = 0; reg < 4; ++reg) {
                int row = m0 + wr * 32 + mf * 16 + lg * 4 + reg;
                int col = n0 + wc * 64 + nf * 16 + lr;
                C[(size_t)row * DMODEL + col] = acc[mf][nf][reg];
            }
}

// ---------------------------------------------------------------------------
// MFMA flash attention, QBLK=128, DEPTH-2 PIPELINE (r13-proven):
// K triple-buffered, V double-buffered, one barrier/iter, counted vmcnt(2)
// in steady state (never drains the in-flight K(t+2) prefetch).
// ---------------------------------------------------------------------------
__global__ __launch_bounds__(256, 3) void attn_mfma(
    const unsigned short* __restrict__ Qc,
    const unsigned short* __restrict__ Kc,
    const unsigned short* __restrict__ Vg,
    unsigned short* __restrict__ attnO,
    unsigned short* __restrict__ OpA,
    unsigned short* __restrict__ OpB,
    float2* __restrict__ ml)
{
    __shared__ __align__(16) unsigned short KsL[3][64 * 64];   // 24 KB
    __shared__ __align__(16) unsigned short VsL[2][64 * 64];   // 16 KB
    __shared__ __align__(16) unsigned short Ps[64 * 64];       //  8 KB

    const int ib = blockIdx.x;          // 0..655
    const int hp = ib & 7;
    const int j  = ib >> 3;             // 0..81
    const int h  = hp * 2 + (j & 1);
    const int item = j >> 1;            // 0..40, heavy-first

    int qb, part, np;
    {
        int i = item;
        if (i < 16)      { np = 4; qb = 15 - (i >> 2); part = i & 3; }
        else if (i < 28) { int jj = i - 16; np = 3; qb = 11 - jj / 3; part = jj % 3; }
        else if (i < 38) { int jj = i - 28; np = 2; qb = 7 - (jj >> 1); part = jj & 1; }
        else             { np = 1; qb = 2 - (i - 38); part = 0; }
    }
    const int nt = 2 * qb + 3;
    const int bsz = nt / np, rem = nt % np;
    const int t0 = part * bsz + (part < rem ? part : rem);
    const int t1 = t0 + bsz + (part < rem ? 1 : 0);   // t1-t0 >= 3 always

    const int q0 = qb * 128;
    const int tid = threadIdx.x, l = tid & 63, w = tid >> 6;
    const int lr = l & 15, lg = l >> 4;

    bf16x8 qa[2][2];
    #pragma unroll
    for (int rg = 0; rg < 2; ++rg) {
        int qr = q0 + w * 32 + rg * 16 + lr;
        qa[rg][0] = *(const bf16x8*)&Qc[((size_t)h * TSEQ + qr) * 64 + lg * 8];
        qa[rg][1] = *(const bf16x8*)&Qc[((size_t)h * TSEQ + qr) * 64 + 32 + lg * 8];
    }

    const int sc8 = (((l & 7) ^ ((l >> 3) & 7))) * 8;
    const int r0s = (w * 2 + 0) * 8 + (l >> 3);
    const int r1s = (w * 2 + 1) * 8 + (l >> 3);
    const unsigned short* Kh = Kc + (((size_t)h * KST) << 6);
    const unsigned short* Vh = Vg + (size_t)h * 64 * KST;

#define STAGE_K(bufi, fk0_) do {                                               \
        gload_lds16(Kh + (((size_t)((fk0_) + r0s)) << 6) + sc8,                \
                    &KsL[bufi][(w * 2 + 0) * 512]);                            \
        gload_lds16(Kh + (((size_t)((fk0_) + r1s)) << 6) + sc8,                \
                    &KsL[bufi][(w * 2 + 1) * 512]);                            \
    } while (0)
#define STAGE_V(bufi, fk0_) do {                                               \
        gload_lds16(Vh + (size_t)r0s * KST + (fk0_) + sc8,                     \
                    &VsL[bufi][(w * 2 + 0) * 512]);                            \
        gload_lds16(Vh + (size_t)r1s * KST + (fk0_) + sc8,                     \
                    &VsL[bufi][(w * 2 + 1) * 512]);                            \
    } while (0)

    f32x4 o[2][4];
    #pragma unroll
    for (int rg = 0; rg < 2; ++rg)
        #pragma unroll
        for (int i = 0; i < 4; ++i) o[rg][i] = (f32x4){0.f, 0.f, 0.f, 0.f};
    float m[2]  = {-1e30f, -1e30f};
    float ll[2] = {0.f, 0.f};

    STAGE_K(t0 % 3, t0 * 64);
    STAGE_V(t0 & 1, t0 * 64);
    STAGE_K((t0 + 1) % 3, (t0 + 1) * 64);
    asm volatile("s_waitcnt vmcnt(2)" ::: "memory");
    __builtin_amdgcn_s_barrier();

    for (int kb = t0; kb < t1; ++kb) {
        const int fk0 = kb * 64;
        const unsigned short* Ksb = &KsL[kb % 3][0];
        const unsigned short* Vsb = &VsL[kb & 1][0];
        const bool moreV = (kb + 1 < t1);
        const bool moreK = (kb + 2 < t1);
        if (moreV) STAGE_V((kb + 1) & 1, fk0 + 64);    // V first (drained at bottom)
        if (moreK) STAGE_K((kb + 2) % 3, fk0 + 128);   // K second (stays in flight)

        bf16x8 vb[2][4];
        #pragma unroll
        for (int ks = 0; ks < 2; ++ks)
            #pragma unroll
            for (int nf = 0; nf < 4; ++nf) {
                int dv = nf * 16 + lr;
                vb[ks][nf] = *(const bf16x8*)
                    &Vsb[dv * 64 + ((lg * 8 + ks * 32) ^ ((dv & 7) << 3))];
            }

        f32x4 sa[2][4];
        #pragma unroll
        for (int rg = 0; rg < 2; ++rg)
            #pragma unroll
            for (int i = 0; i < 4; ++i) sa[rg][i] = (f32x4){0.f, 0.f, 0.f, 0.f};
        #pragma unroll
        for (int ks = 0; ks < 2; ++ks) {
            int dd = lg * 8 + ks * 32;
            #pragma unroll
            for (int nf = 0; nf < 4; ++nf) {
                int kkc = nf * 16 + lr;
                bf16x8 kbf = *(const bf16x8*)&Ksb[kkc * 64 + (dd ^ ((kkc & 7) << 3))];
                sa[0][nf] = __builtin_amdgcn_mfma_f32_16x16x32_bf16(kbf, qa[0][ks], sa[0][nf], 0, 0, 0);
                sa[1][nf] = __builtin_amdgcn_mfma_f32_16x16x32_bf16(kbf, qa[1][ks], sa[1][nf], 0, 0, 0);
            }
        }

        const bool needmask = (fk0 + 62 > q0 + w * 32);
        const int pr = w * 16 + lr;
        const int psw = (pr & 7) << 3;
        #pragma unroll
        for (int rg = 0; rg < 2; ++rg) {
            const int q = q0 + w * 32 + rg * 16 + lr;
            float mt = -1e30f;
            if (needmask) {
                #pragma unroll
                for (int nf = 0; nf < 4; ++nf)
                    #pragma unroll
                    for (int reg = 0; reg < 4; ++reg) {
                        int fk = fk0 + nf * 16 + lg * 4 + reg;
                        float val = (fk <= q + 1) ? sa[rg][nf][reg] : -1e9f;
                        sa[rg][nf][reg] = val;
                        mt = fmaxf(mt, val);
                    }
            } else {
                #pragma unroll
                for (int nf = 0; nf < 4; ++nf)
                    #pragma unroll
                    for (int reg = 0; reg < 4; ++reg)
                        mt = fmaxf(mt, sa[rg][nf][reg]);
            }
            mt = fmaxf(mt, __shfl_xor(mt, 16, 64));
            mt = fmaxf(mt, __shfl_xor(mt, 32, 64));
            if (__any(mt > m[rg] + 8.0f)) {       // T13 defer-max
                float mn = fmaxf(m[rg], mt);
                float alpha = __expf(m[rg] - mn);
                m[rg] = mn;
                ll[rg] *= alpha;
                #pragma unroll
                for (int nf = 0; nf < 4; ++nf)
                    #pragma unroll
                    for (int reg = 0; reg < 4; ++reg)
                        o[rg][nf][reg] *= alpha;
            }
            float rs = 0.0f;
            #pragma unroll
            for (int nf = 0; nf < 4; ++nf)
                #pragma unroll
                for (int reg = 0; reg < 4; ++reg) {
                    float p = __expf(sa[rg][nf][reg] - m[rg]);
                    sa[rg][nf][reg] = p;
                    rs += p;
                }
            rs += __shfl_xor(rs, 16, 64);
            rs += __shfl_xor(rs, 32, 64);
            ll[rg] += rs;

            #pragma unroll
            for (int nf = 0; nf < 4; ++nf) {
                bf16x4 pk;
                pk[0] = f2bf(sa[rg][nf][0]); pk[1] = f2bf(sa[rg][nf][1]);
                pk[2] = f2bf(sa[rg][nf][2]); pk[3] = f2bf(sa[rg][nf][3]);
                int kk0 = nf * 16 + lg * 4;
                *(bf16x4*)&Ps[pr * 64 + (kk0 ^ psw)] = pk;
            }
            #pragma unroll
            for (int ks = 0; ks < 2; ++ks) {
                int kk0 = lg * 8 + ks * 32;
                bf16x8 pa = *(const bf16x8*)&Ps[pr * 64 + (kk0 ^ psw)];
                #pragma unroll
                for (int nf = 0; nf < 4; ++nf)
                    o[rg][nf] = __builtin_amdgcn_mfma_f32_16x16x32_bf16(
                        vb[ks][nf], pa, o[rg][nf], 0, 0, 0);
            }
        }

        if (moreK) { asm volatile("s_waitcnt vmcnt(2)" ::: "memory"); }
        else       { asm volatile("s_waitcnt vmcnt(0)" ::: "memory"); }
        __builtin_amdgcn_s_barrier();
    }
#undef STAGE_K
#undef STAGE_V

    const int sidx = h * 38 + item;
    unsigned short* Od = (np == 1) ? 0
        : ((sidx < 384) ? OpA + (size_t)sidx * 8192
                        : OpB + (size_t)(sidx - 384) * 8192);
    #pragma unroll
    for (int rg = 0; rg < 2; ++rg) {
        const float inv = 1.0f / ll[rg];
        const int q = q0 + w * 32 + rg * 16 + lr;
        if (np == 1) {
            #pragma unroll
            for (int nf = 0; nf < 4; ++nf) {
                ushort4 ov;
                ov.x = f2bf(o[rg][nf][0] * inv); ov.y = f2bf(o[rg][nf][1] * inv);
                ov.z = f2bf(o[rg][nf][2] * inv); ov.w = f2bf(o[rg][nf][3] * inv);
                *(ushort4*)&attnO[(size_t)q * DMODEL + h * 64 + nf * 16 + lg * 4] = ov;
            }
        } else {
            const int r = w * 32 + rg * 16 + lr;
            #pragma unroll
            for (int nf = 0; nf < 4; ++nf) {
                ushort4 ov;
                ov.x = f2bf(o[rg][nf][0] * inv); ov.y = f2bf(o[rg][nf][1] * inv);
                ov.z = f2bf(o[rg][nf][2] * inv); ov.w = f2bf(o[rg][nf][3] * inv);
                *(ushort4*)&Od[r * 64 + nf * 16 + lg * 4] = ov;
            }
            if (lg == 0)
                ml[sidx * 128 + r] = make_float2(m[rg], ll[rg]);
        }
    }
}

// ---------------------------------------------------------------------------
// Combine split partials: one block per (h, qb in [3,16)). np in {2,3,4}.
// ---------------------------------------------------------------------------
__global__ __launch_bounds__(256) void combine_wave(
    const unsigned short* __restrict__ OpA,
    const unsigned short* __restrict__ OpB,
    const float2* __restrict__ ml,
    unsigned short* __restrict__ attnO)
{
    const int qb = 3 + blockIdx.x;   // 3..15
    const int h  = blockIdx.y;
    int np, i0;
    if (qb >= 12)     { np = 4; i0 = (15 - qb) * 4; }
    else if (qb >= 8) { np = 3; i0 = 16 + (11 - qb) * 3; }
    else              { np = 2; i0 = 28 + (7 - qb) * 2; }
    const int sidx0 = h * 38 + i0;

    const int t = threadIdx.x;
    const int r = t & 127, dv0 = (t >> 7) * 32;

    float wt[4];
    float mm = -1e30f;
    #pragma unroll
    for (int p = 0; p < 4; ++p)
        if (p < np) mm = fmaxf(mm, ml[(sidx0 + p) * 128 + r].x);
    float tot = 0.0f;
    #pragma unroll
    for (int p = 0; p < 4; ++p) {
        wt[p] = 0.0f;
        if (p < np) {
            float2 v = ml[(sidx0 + p) * 128 + r];
            wt[p] = v.y * __expf(v.x - mm);
            tot += wt[p];
        }
    }
    const float inv = 1.0f / tot;

    float accv[32];
    #pragma unroll
    for (int c = 0; c < 32; ++c) accv[c] = 0.0f;
    #pragma unroll
    for (int p = 0; p < 4; ++p) {
        if (p < np) {
            int s = sidx0 + p;
            const unsigned short* Od = (s < 384)
                ? OpA + (size_t)s * 8192
                : OpB + (size_t)(s - 384) * 8192;
            #pragma unroll
            for (int c4 = 0; c4 < 8; ++c4) {
                ushort4 v = *(const ushort4*)&Od[r * 64 + dv0 + c4 * 4];
                accv[c4 * 4 + 0] += wt[p] * bf2f(v.x);
                accv[c4 * 4 + 1] += wt[p] * bf2f(v.y);
                accv[c4 * 4 + 2] += wt[p] * bf2f(v.z);
                accv[c4 * 4 + 3] += wt[p] * bf2f(v.w);
            }
        }
    }
    const int q = qb * 128 + r;
    #pragma unroll
    for (int c4 = 0; c4 < 8; ++c4) {
        ushort4 ov;
        ov.x = f2bf(accv[c4 * 4 + 0] * inv);
        ov.y = f2bf(accv[c4 * 4 + 1] * inv);
        ov.z = f2bf(accv[c4 * 4 + 2] * inv);
        ov.w = f2bf(accv[c4 * 4 + 3] * inv);
        *(ushort4*)&attnO[(size_t)q * DMODEL + h * 64 + dv0 + c4 * 4] = ov;
    }
}

// ---------------------------------------------------------------------------
extern "C" void kernel_launch(void* const* d_in, const int* in_sizes, int n_in,
                              void* d_out, int out_size, void* d_ws, size_t ws_size,
                              hipStream_t stream)
{
    const float* x      = (const float*)d_in[0];
    const float* wq_sem = (const float*)d_in[1];
    const float* wk_sem = (const float*)d_in[2];
    const float* wq_geo = (const float*)d_in[3];
    const float* wk_geo = (const float*)d_in[4];
    const float* wv     = (const float*)d_in[5];
    const float* wo     = (const float*)d_in[6];
    const float* ksn    = (const float*)d_in[7];
    const float* kgn    = (const float*)d_in[8];
    const float* vn     = (const float*)d_in[9];
    float* out = (float*)d_out;

    // Workspace (peak 29.7 MiB):
    //  [0,        4.19M)  Xb -> attnO
    //  [4.19M,   10.49M)  WcatT -> OpA (384 partials x 16KB)
    //  [10.49M,  12.58M)  WoT
    //  [12.58M,  16.78M)  Qc  [16][2048][64]
    //  [16.78M,  21.10M)  Kc  [16][2112][64]
    //  [21.10M,  25.43M)  Vg  [16][64][2112]
    //  [25.43M,  29.10M)  OpB (224 partials x 16KB)
    //  [29.10M,  29.72M)  ml  float2 [608][128]
    char* ws = (char*)d_ws;
    unsigned short* Xb    = (unsigned short*)(ws);
    unsigned short* attnO = (unsigned short*)(ws);
    unsigned short* WcatT = (unsigned short*)(ws + 4194304);
    unsigned short* OpA   = (unsigned short*)(ws + 4194304);
    unsigned short* WoT   = (unsigned short*)(ws + 10485760);
    unsigned short* Qc    = (unsigned short*)(ws + 12582912);
    unsigned short* Kc    = (unsigned short*)(ws + 16777216);
    unsigned short* Vg    = (unsigned short*)(ws + 21102592);
    unsigned short* OpB   = (unsigned short*)(ws + 25427968);
    float2*         ml    = (float2*)(ws + 29097984);

    prep_all<<<3600, 256, 0, stream>>>(x, wq_sem, wk_sem, wq_geo, wk_geo, wv, wo,
                                       ksn, kgn, vn, Xb, WcatT, WoT, Kc, Vg);

    gemm_proj_fused<<<dim3(24, 32), 256, 0, stream>>>(Xb, WcatT, Qc, Kc, Vg);

    attn_mfma<<<656, 256, 0, stream>>>(Qc, Kc, Vg, attnO, OpA, OpB, ml);
    combine_wave<<<dim3(13, NHEAD), 256, 0, stream>>>(OpA, OpB, ml, attnO);

    gemm_out<<<dim3(8, 32), 256, 0, stream>>>(attnO, WoT, out);
}

// Round 17
// 82.109 us; speedup vs baseline: 2.3647x; 1.0222x over previous
//
#include <hip/hip_runtime.h>
#include <hip/hip_bf16.h>

typedef __hip_bfloat16 bf16;
typedef __attribute__((ext_vector_type(8))) short bf16x8;   // 8 bf16 = 4 VGPR (MFMA A/B frag)
typedef __attribute__((ext_vector_type(4))) short bf16x4;   // 4 bf16 = 8B
typedef __attribute__((ext_vector_type(4))) float f32x4;    // MFMA C/D frag

#define TSEQ   2048
#define DMODEL 1024
#define NHEAD  16
#define KST    2112   // padded key count (2049 real, zero-padded), 33*64
#define SCALE  0.17677669529663687f  // 1/sqrt(32) == sem_scale == geo_scale
#define LN1E4_16 0.5756462732485115f // ln(10000)/16

__device__ __forceinline__ unsigned short f2bf(float f) {
    union { bf16 h; unsigned short u; } x;
    x.h = __float2bfloat16(f);
    return x.u;
}
__device__ __forceinline__ float bf2f(unsigned short u) {
    return __uint_as_float(((unsigned int)u) << 16);
}

__device__ __forceinline__ void gload_lds16(const void* g, void* l) {
    __builtin_amdgcn_global_load_lds(
        (const __attribute__((address_space(1))) void*)g,
        (__attribute__((address_space(3))) void*)l, 16, 0, 0);
}

// ---------------------------------------------------------------------------
// prep_all: one launch for X convert (bx<2048), 6 weight transposes
// (bx in [2048,3584)), and null/pad init (bx >= 3584).
// ---------------------------------------------------------------------------
__global__ __launch_bounds__(256) void prep_all(
    const float* __restrict__ X,
    const float* __restrict__ wqs, const float* __restrict__ wks,
    const float* __restrict__ wqg, const float* __restrict__ wkg,
    const float* __restrict__ wv,  const float* __restrict__ wo,
    const float* __restrict__ ksn, const float* __restrict__ kgn,
    const float* __restrict__ vn,
    unsigned short* __restrict__ Xb,
    unsigned short* __restrict__ WcatT, unsigned short* __restrict__ WoT,
    unsigned short* __restrict__ Kc, unsigned short* __restrict__ Vg)
{
    __shared__ float T[64][65];
    const int bx = blockIdx.x;
    const int tid = threadIdx.x;
    if (bx < 2048) {
        int i = (bx * 256 + tid) * 4;
        float4 v = *(const float4*)(X + i);
        ushort4 o;
        o.x = f2bf(v.x); o.y = f2bf(v.y); o.z = f2bf(v.z); o.w = f2bf(v.w);
        *(ushort4*)(Xb + i) = o;
    } else if (bx < 3584) {
        const int idx = bx - 2048;
        const int z = idx >> 8, rem = idx & 255;
        const int cx = rem & 15, ry = rem >> 4;
        const float* src; unsigned short* dst; int C;
        switch (z) {
            case 0: src = wqs; dst = WcatT;               C = 512;  break;
            case 1: src = wks; dst = WcatT + 512  * 1024; C = 512;  break;
            case 2: src = wqg; dst = WcatT + 1024 * 1024; C = 512;  break;
            case 3: src = wkg; dst = WcatT + 1536 * 1024; C = 512;  break;
            case 4: src = wv;  dst = WcatT + 2048 * 1024; C = 1024; break;
            default: src = wo; dst = WoT;                 C = 1024; break;
        }
        const int c0 = cx * 64;
        if (c0 >= C) return;
        const int r0 = ry * 64;
        #pragma unroll
        for (int i = 0; i < 16; ++i) {
            int id2 = tid + 256 * i;
            int r = id2 >> 6, c = id2 & 63;
            T[r][c] = src[(size_t)(r0 + r) * C + c0 + c];
        }
        __syncthreads();
        #pragma unroll
        for (int i = 0; i < 16; ++i) {
            int id2 = tid + 256 * i;
            int cc = id2 >> 6, rr = id2 & 63;
            dst[(size_t)(c0 + cc) * 1024 + r0 + rr] = f2bf(T[rr][cc]);
        }
    } else {
        const int h = bx - 3584;
        const int d = tid & 63, g = tid >> 6;
        if (g == 0)
            Kc[((size_t)h * KST + 0) * 64 + d] =
                f2bf(d < 32 ? ksn[h * 32 + d] : kgn[h * 32 + d - 32]);
        if (g == 1)
            Vg[((size_t)h * 64 + d) * KST + 0] = f2bf(vn[h * 64 + d]);
        for (int fk = 2049 + g; fk < KST; fk += 4) {
            Kc[((size_t)h * KST + fk) * 64 + d] = 0;
            Vg[((size_t)h * 64 + d) * KST + fk] = 0;
        }
    }
}

// ---------------------------------------------------------------------------
// Fused projection GEMM: 64x128 tile, BK=64, single-buffer swizzled LDS.
// Epilogue writes attention layouts (Qc pre-scaled, RoPE fused).
// ---------------------------------------------------------------------------
__global__ __launch_bounds__(256) void gemm_proj_fused(
    const unsigned short* __restrict__ A,   // Xb [2048][1024]
    const unsigned short* __restrict__ Bt,  // WcatT [3072][1024]
    unsigned short* __restrict__ Qc,
    unsigned short* __restrict__ Kc,
    unsigned short* __restrict__ Vg)
{
    __shared__ __align__(16) unsigned short Abuf[64 * 64];    //  8 KB
    __shared__ __align__(16) unsigned short Bbuf[128 * 64];   // 16 KB
    const int n0 = blockIdx.x * 128, m0 = blockIdx.y * 64;
    const int tid = threadIdx.x, l = tid & 63, wv = tid >> 6;
    const int wr = wv >> 1, wc = wv & 1;      // wave tile: 32 rows x 64 cols
    const int lr = l & 15, lg = l >> 4;

    f32x4 acc[2][4];
    #pragma unroll
    for (int i = 0; i < 2; ++i)
        #pragma unroll
        for (int j = 0; j < 4; ++j) acc[i][j] = (f32x4){0.f, 0.f, 0.f, 0.f};

    for (int k0 = 0; k0 < 1024; k0 += 64) {
        #pragma unroll
        for (int i = 0; i < 2; ++i) {              // A: 2 chunks/thread
            int c = wv * 128 + i * 64 + l;
            int row = c >> 3, sseg = (c & 7) ^ (row & 7);
            gload_lds16(A + (size_t)(m0 + row) * 1024 + k0 + sseg * 8,
                        &Abuf[(wv * 128 + i * 64) * 8]);
        }
        #pragma unroll
        for (int i = 0; i < 4; ++i) {              // B: 4 chunks/thread
            int c = wv * 256 + i * 64 + l;
            int row = c >> 3, sseg = (c & 7) ^ (row & 7);
            gload_lds16(Bt + (size_t)(n0 + row) * 1024 + k0 + sseg * 8,
                        &Bbuf[(wv * 256 + i * 64) * 8]);
        }
        __syncthreads();
        #pragma unroll
        for (int ks = 0; ks < 2; ++ks) {
            bf16x8 af[2], bfv[4];
            #pragma unroll
            for (int mf = 0; mf < 2; ++mf) {
                int rr = wr * 32 + mf * 16 + lr;
                int seg = (ks * 4 + lg) ^ (rr & 7);
                af[mf] = *(const bf16x8*)&Abuf[rr * 64 + seg * 8];
            }
            #pragma unroll
            for (int nf = 0; nf < 4; ++nf) {
                int rr = wc * 64 + nf * 16 + lr;
                int seg = (ks * 4 + lg) ^ (rr & 7);
                bfv[nf] = *(const bf16x8*)&Bbuf[rr * 64 + seg * 8];
            }
            #pragma unroll
            for (int mf = 0; mf < 2; ++mf)
                #pragma unroll
                for (int nf = 0; nf < 4; ++nf)
                    acc[mf][nf] = __builtin_amdgcn_mfma_f32_16x16x32_bf16(
                        af[mf], bfv[nf], acc[mf][nf], 0, 0, 0);
        }
        __syncthreads();
    }

    const int sec = n0 >> 9;   // 0 qs | 1 ks | 2 qg | 3 kg | 4,5 v
    if (sec <= 1) {
        unsigned short* dst = (sec == 0) ? Qc : Kc;
        const int tstr  = (sec == 0) ? TSEQ : KST;
        const int fkoff = (sec == 0) ? 0 : 1;
        const float sc  = (sec == 0) ? SCALE : 1.0f;
        #pragma unroll
        for (int mf = 0; mf < 2; ++mf)
            #pragma unroll
            for (int nf = 0; nf < 4; ++nf) {
                int col = (n0 & 511) + wc * 64 + nf * 16 + lr;
                int h = col >> 5, d = col & 31;
                #pragma unroll
                for (int reg = 0; reg < 4; ++reg) {
                    int q = m0 + wr * 32 + mf * 16 + lg * 4 + reg;
                    dst[((size_t)h * tstr + q + fkoff) * 64 + d] =
                        f2bf(acc[mf][nf][reg] * sc);
                }
            }
    } else if (sec <= 3) {
        unsigned short* dst = (sec == 2) ? Qc : Kc;
        const int tstr  = (sec == 2) ? TSEQ : KST;
        const int fkoff = (sec == 2) ? 0 : 1;
        const float sc  = (sec == 2) ? SCALE : 1.0f;
        const float invf = __expf(-(float)lr * LN1E4_16);
        #pragma unroll
        for (int mf = 0; mf < 2; ++mf)
            #pragma unroll
            for (int reg = 0; reg < 4; ++reg) {
                int q = m0 + wr * 32 + mf * 16 + lg * 4 + reg;
                float s, c;
                __sincosf((float)q * invf, &s, &c);
                #pragma unroll
                for (int nfp = 0; nfp < 2; ++nfp) {
                    int nf0 = nfp * 2;
                    int colbase = (n0 & 511) + wc * 64 + nf0 * 16;
                    int h = colbase >> 5;
                    float x1 = acc[mf][nf0][reg], x2 = acc[mf][nf0 + 1][reg];
                    size_t base = ((size_t)h * tstr + q + fkoff) * 64 + 32;
                    dst[base + lr]      = f2bf((x1 * c - x2 * s) * sc);
                    dst[base + lr + 16] = f2bf((x2 * c + x1 * s) * sc);
                }
            }
    } else {
        #pragma unroll
        for (int nf = 0; nf < 4; ++nf) {
            int colr = (n0 - 2048) + wc * 64 + nf * 16 + lr;
            int h = colr >> 6, dv = colr & 63;
            size_t rowbase = ((size_t)h * 64 + dv) * KST;
            #pragma unroll
            for (int mf = 0; mf < 2; ++mf)
                #pragma unroll
                for (int reg = 0; reg < 4; ++reg) {
                    int q = m0 + wr * 32 + mf * 16 + lg * 4 + reg;
                    Vg[rowbase + q + 1] = f2bf(acc[mf][nf][reg]);
                }
        }
    }
}

// ---------------------------------------------------------------------------
// Output GEMM: 64x128 tile, BK=64, single-buffer swizzled LDS.
// ---------------------------------------------------------------------------
__global__ __launch_bounds__(256) void gemm_out(const unsigned short* __restrict__ A,
                                                const unsigned short* __restrict__ Bt,
                                                float* __restrict__ C)
{
    __shared__ __align__(16) unsigned short Abuf[64 * 64];
    __shared__ __align__(16) unsigned short Bbuf[128 * 64];
    const int n0 = blockIdx.x * 128, m0 = blockIdx.y * 64;
    const int tid = threadIdx.x, l = tid & 63, wv = tid >> 6;
    const int wr = wv >> 1, wc = wv & 1;
    const int lr = l & 15, lg = l >> 4;

    f32x4 acc[2][4];
    #pragma unroll
    for (int i = 0; i < 2; ++i)
        #pragma unroll
        for (int j = 0; j < 4; ++j) acc[i][j] = (f32x4){0.f, 0.f, 0.f, 0.f};

    for (int k0 = 0; k0 < 1024; k0 += 64) {
        #pragma unroll
        for (int i = 0; i < 2; ++i) {
            int c = wv * 128 + i * 64 + l;
            int row = c >> 3, sseg = (c & 7) ^ (row & 7);
            gload_lds16(A + (size_t)(m0 + row) * 1024 + k0 + sseg * 8,
                        &Abuf[(wv * 128 + i * 64) * 8]);
        }
        #pragma unroll
        for (int i = 0; i < 4; ++i) {
            int c = wv * 256 + i * 64 + l;
            int row = c >> 3, sseg = (c & 7) ^ (row & 7);
            gload_lds16(Bt + (size_t)(n0 + row) * 1024 + k0 + sseg * 8,
                        &Bbuf[(wv * 256 + i * 64) * 8]);
        }
        __syncthreads();
        #pragma unroll
        for (int ks = 0; ks < 2; ++ks) {
            bf16x8 af[2], bfv[4];
            #pragma unroll
            for (int mf = 0; mf < 2; ++mf) {
                int rr = wr * 32 + mf * 16 + lr;
                int seg = (ks * 4 + lg) ^ (rr & 7);
                af[mf] = *(const bf16x8*)&Abuf[rr * 64 + seg * 8];
            }
            #pragma unroll
            for (int nf = 0; nf < 4; ++nf) {
                int rr = wc * 64 + nf * 16 + lr;
                int seg = (ks * 4 + lg) ^ (rr & 7);
                bfv[nf] = *(const bf16x8*)&Bbuf[rr * 64 + seg * 8];
            }
            #pragma unroll
            for (int mf = 0; mf < 2; ++mf)
                #pragma unroll
                for (int nf = 0; nf < 4; ++nf)
                    acc[mf][nf] = __builtin_amdgcn_mfma_f32_16x16x32_bf16(
                        af[mf], bfv[nf], acc[mf][nf], 0, 0, 0);
        }
        __syncthreads();
    }
    #pragma unroll
    for (int mf = 0; mf < 2; ++mf)
        #pragma unroll
        for (int nf = 0; nf < 4; ++nf)
            #pragma unroll
            for (int reg = 0; reg < 4; ++reg) {
                int row = m0 + wr * 32 + mf * 16 + lg * 4 + reg;
                int col = n0 + wc * 64 + nf * 16 + lr;
                C[(size_t)row * DMODEL + col] = acc[mf][nf][reg];
            }
}

// ---------------------------------------------------------------------------
// MFMA flash attention, QBLK=128, depth-2 pipeline (r13-proven), with the
// per-iter phases RESCHEDULED to hide the Ps write->read DS round-trip:
//   softmax(rg0) -> write Ps(rg0) -> softmax(rg1)   [VALU covers DS latency]
//   -> PV(rg0) -> write Ps(rg1) -> PV(rg1)
// Same-wave DS ordering guarantees PV(rg0) reads complete before the rg1
// write overwrites the shared Ps rows.
// ---------------------------------------------------------------------------
__global__ __launch_bounds__(256, 3) void attn_mfma(
    const unsigned short* __restrict__ Qc,
    const unsigned short* __restrict__ Kc,
    const unsigned short* __restrict__ Vg,
    unsigned short* __restrict__ attnO,
    unsigned short* __restrict__ OpA,
    unsigned short* __restrict__ OpB,
    float2* __restrict__ ml)
{
    __shared__ __align__(16) unsigned short KsL[3][64 * 64];   // 24 KB
    __shared__ __align__(16) unsigned short VsL[2][64 * 64];   // 16 KB
    __shared__ __align__(16) unsigned short Ps[64 * 64];       //  8 KB

    const int ib = blockIdx.x;          // 0..655
    const int hp = ib & 7;
    const int j  = ib >> 3;             // 0..81
    const int h  = hp * 2 + (j & 1);
    const int item = j >> 1;            // 0..40, heavy-first

    int qb, part, np;
    {
        int i = item;
        if (i < 16)      { np = 4; qb = 15 - (i >> 2); part = i & 3; }
        else if (i < 28) { int jj = i - 16; np = 3; qb = 11 - jj / 3; part = jj % 3; }
        else if (i < 38) { int jj = i - 28; np = 2; qb = 7 - (jj >> 1); part = jj & 1; }
        else             { np = 1; qb = 2 - (i - 38); part = 0; }
    }
    const int nt = 2 * qb + 3;
    const int bsz = nt / np, rem = nt % np;
    const int t0 = part * bsz + (part < rem ? part : rem);
    const int t1 = t0 + bsz + (part < rem ? 1 : 0);   // t1-t0 >= 3 always

    const int q0 = qb * 128;
    const int tid = threadIdx.x, l = tid & 63, w = tid >> 6;
    const int lr = l & 15, lg = l >> 4;

    bf16x8 qa[2][2];
    #pragma unroll
    for (int rg = 0; rg < 2; ++rg) {
        int qr = q0 + w * 32 + rg * 16 + lr;
        qa[rg][0] = *(const bf16x8*)&Qc[((size_t)h * TSEQ + qr) * 64 + lg * 8];
        qa[rg][1] = *(const bf16x8*)&Qc[((size_t)h * TSEQ + qr) * 64 + 32 + lg * 8];
    }

    const int sc8 = (((l & 7) ^ ((l >> 3) & 7))) * 8;
    const int r0s = (w * 2 + 0) * 8 + (l >> 3);
    const int r1s = (w * 2 + 1) * 8 + (l >> 3);
    const unsigned short* Kh = Kc + (((size_t)h * KST) << 6);
    const unsigned short* Vh = Vg + (size_t)h * 64 * KST;

#define STAGE_K(bufi, fk0_) do {                                               \
        gload_lds16(Kh + (((size_t)((fk0_) + r0s)) << 6) + sc8,                \
                    &KsL[bufi][(w * 2 + 0) * 512]);                            \
        gload_lds16(Kh + (((size_t)((fk0_) + r1s)) << 6) + sc8,                \
                    &KsL[bufi][(w * 2 + 1) * 512]);                            \
    } while (0)
#define STAGE_V(bufi, fk0_) do {                                               \
        gload_lds16(Vh + (size_t)r0s * KST + (fk0_) + sc8,                     \
                    &VsL[bufi][(w * 2 + 0) * 512]);                            \
        gload_lds16(Vh + (size_t)r1s * KST + (fk0_) + sc8,                     \
                    &VsL[bufi][(w * 2 + 1) * 512]);                            \
    } while (0)

    f32x4 o[2][4];
    #pragma unroll
    for (int rg = 0; rg < 2; ++rg)
        #pragma unroll
        for (int i = 0; i < 4; ++i) o[rg][i] = (f32x4){0.f, 0.f, 0.f, 0.f};
    float m[2]  = {-1e30f, -1e30f};
    float ll[2] = {0.f, 0.f};

    STAGE_K(t0 % 3, t0 * 64);
    STAGE_V(t0 & 1, t0 * 64);
    STAGE_K((t0 + 1) % 3, (t0 + 1) * 64);
    asm volatile("s_waitcnt vmcnt(2)" ::: "memory");
    __builtin_amdgcn_s_barrier();

    for (int kb = t0; kb < t1; ++kb) {
        const int fk0 = kb * 64;
        const unsigned short* Ksb = &KsL[kb % 3][0];
        const unsigned short* Vsb = &VsL[kb & 1][0];
        const bool moreV = (kb + 1 < t1);
        const bool moreK = (kb + 2 < t1);
        if (moreV) STAGE_V((kb + 1) & 1, fk0 + 64);    // V first (drained at bottom)
        if (moreK) STAGE_K((kb + 2) % 3, fk0 + 128);   // K second (stays in flight)

        bf16x8 vb[2][4];
        #pragma unroll
        for (int ks = 0; ks < 2; ++ks)
            #pragma unroll
            for (int nf = 0; nf < 4; ++nf) {
                int dv = nf * 16 + lr;
                vb[ks][nf] = *(const bf16x8*)
                    &Vsb[dv * 64 + ((lg * 8 + ks * 32) ^ ((dv & 7) << 3))];
            }

        f32x4 sa[2][4];
        #pragma unroll
        for (int rg = 0; rg < 2; ++rg)
            #pragma unroll
            for (int i = 0; i < 4; ++i) sa[rg][i] = (f32x4){0.f, 0.f, 0.f, 0.f};
        #pragma unroll
        for (int ks = 0; ks < 2; ++ks) {
            int dd = lg * 8 + ks * 32;
            #pragma unroll
            for (int nf = 0; nf < 4; ++nf) {
                int kkc = nf * 16 + lr;
                bf16x8 kbf = *(const bf16x8*)&Ksb[kkc * 64 + (dd ^ ((kkc & 7) << 3))];
                sa[0][nf] = __builtin_amdgcn_mfma_f32_16x16x32_bf16(kbf, qa[0][ks], sa[0][nf], 0, 0, 0);
                sa[1][nf] = __builtin_amdgcn_mfma_f32_16x16x32_bf16(kbf, qa[1][ks], sa[1][nf], 0, 0, 0);
            }
        }

        const bool needmask = (fk0 + 62 > q0 + w * 32);
        const int pr = w * 16 + lr;
        const int psw = (pr & 7) << 3;

#define SOFTMAX_RG(RG) do {                                                    \
        const int q = q0 + w * 32 + (RG) * 16 + lr;                            \
        float mt = -1e30f;                                                     \
        if (needmask) {                                                        \
            _Pragma("unroll")                                                  \
            for (int nf = 0; nf < 4; ++nf)                                     \
                _Pragma("unroll")                                              \
                for (int reg = 0; reg < 4; ++reg) {                            \
                    int fk = fk0 + nf * 16 + lg * 4 + reg;                     \
                    float val = (fk <= q + 1) ? sa[RG][nf][reg] : -1e9f;       \
                    sa[RG][nf][reg] = val;                                     \
                    mt = fmaxf(mt, val);                                       \
                }                                                              \
        } else {                                                               \
            _Pragma("unroll")                                                  \
            for (int nf = 0; nf < 4; ++nf)                                     \
                _Pragma("unroll")                                              \
                for (int reg = 0; reg < 4; ++reg)                              \
                    mt = fmaxf(mt, sa[RG][nf][reg]);                           \
        }                                                                      \
        mt = fmaxf(mt, __shfl_xor(mt, 16, 64));                                \
        mt = fmaxf(mt, __shfl_xor(mt, 32, 64));                                \
        if (__any(mt > m[RG] + 8.0f)) {                                        \
            float mn = fmaxf(m[RG], mt);                                       \
            float alpha = __expf(m[RG] - mn);                                  \
            m[RG] = mn;                                                        \
            ll[RG] *= alpha;                                                   \
            _Pragma("unroll")                                                  \
            for (int nf = 0; nf < 4; ++nf)                                     \
                _Pragma("unroll")                                              \
                for (int reg = 0; reg < 4; ++reg)                              \
                    o[RG][nf][reg] *= alpha;                                   \
        }                                                                      \
        float rs = 0.0f;                                                       \
        _Pragma("unroll")                                                      \
        for (int nf = 0; nf < 4; ++nf)                                         \
            _Pragma("unroll")                                                  \
            for (int reg = 0; reg < 4; ++reg) {                                \
                float p = __expf(sa[RG][nf][reg] - m[RG]);                     \
                sa[RG][nf][reg] = p;                                           \
                rs += p;                                                       \
            }                                                                  \
        rs += __shfl_xor(rs, 16, 64);                                          \
        rs += __shfl_xor(rs, 32, 64);                                          \
        ll[RG] += rs;                                                          \
    } while (0)

#define WRITE_PS(RG) do {                                                      \
        _Pragma("unroll")                                                      \
        for (int nf = 0; nf < 4; ++nf) {                                       \
            bf16x4 pk;                                                         \
            pk[0] = f2bf(sa[RG][nf][0]); pk[1] = f2bf(sa[RG][nf][1]);          \
            pk[2] = f2bf(sa[RG][nf][2]); pk[3] = f2bf(sa[RG][nf][3]);          \
            int kk0 = nf * 16 + lg * 4;                                        \
            *(bf16x4*)&Ps[pr * 64 + (kk0 ^ psw)] = pk;                         \
        }                                                                      \
    } while (0)

#define PV_RG(RG) do {                                                         \
        _Pragma("unroll")                                                      \
        for (int ks = 0; ks < 2; ++ks) {                                       \
            int kk0 = lg * 8 + ks * 32;                                        \
            bf16x8 pa = *(const bf16x8*)&Ps[pr * 64 + (kk0 ^ psw)];            \
            _Pragma("unroll")                                                  \
            for (int nf = 0; nf < 4; ++nf)                                     \
                o[RG][nf] = __builtin_amdgcn_mfma_f32_16x16x32_bf16(           \
                    vb[ks][nf], pa, o[RG][nf], 0, 0, 0);                       \
        }                                                                      \
    } while (0)

        SOFTMAX_RG(0);
        WRITE_PS(0);
        SOFTMAX_RG(1);     // VALU work hides rg0's Ps write->read DS latency
        PV_RG(0);
        WRITE_PS(1);       // same-wave DS order: after PV_RG(0)'s reads
        PV_RG(1);

#undef SOFTMAX_RG
#undef WRITE_PS
#undef PV_RG

        if (moreK) { asm volatile("s_waitcnt vmcnt(2)" ::: "memory"); }
        else       { asm volatile("s_waitcnt vmcnt(0)" ::: "memory"); }
        __builtin_amdgcn_s_barrier();
    }
#undef STAGE_K
#undef STAGE_V

    const int sidx = h * 38 + item;
    unsigned short* Od = (np == 1) ? 0
        : ((sidx < 384) ? OpA + (size_t)sidx * 8192
                        : OpB + (size_t)(sidx - 384) * 8192);
    #pragma unroll
    for (int rg = 0; rg < 2; ++rg) {
        const float inv = 1.0f / ll[rg];
        const int q = q0 + w * 32 + rg * 16 + lr;
        if (np == 1) {
            #pragma unroll
            for (int nf = 0; nf < 4; ++nf) {
                ushort4 ov;
                ov.x = f2bf(o[rg][nf][0] * inv); ov.y = f2bf(o[rg][nf][1] * inv);
                ov.z = f2bf(o[rg][nf][2] * inv); ov.w = f2bf(o[rg][nf][3] * inv);
                *(ushort4*)&attnO[(size_t)q * DMODEL + h * 64 + nf * 16 + lg * 4] = ov;
            }
        } else {
            const int r = w * 32 + rg * 16 + lr;
            #pragma unroll
            for (int nf = 0; nf < 4; ++nf) {
                ushort4 ov;
                ov.x = f2bf(o[rg][nf][0] * inv); ov.y = f2bf(o[rg][nf][1] * inv);
                ov.z = f2bf(o[rg][nf][2] * inv); ov.w = f2bf(o[rg][nf][3] * inv);
                *(ushort4*)&Od[r * 64 + nf * 16 + lg * 4] = ov;
            }
            if (lg == 0)
                ml[sidx * 128 + r] = make_float2(m[rg], ll[rg]);
        }
    }
}

// ---------------------------------------------------------------------------
// Combine split partials: one block per (h, qb in [3,16)). np in {2,3,4}.
// ---------------------------------------------------------------------------
__global__ __launch_bounds__(256) void combine_wave(
    const unsigned short* __restrict__ OpA,
    const unsigned short* __restrict__ OpB,
    const float2* __restrict__ ml,
    unsigned short* __restrict__ attnO)
{
    const int qb = 3 + blockIdx.x;   // 3..15
    const int h  = blockIdx.y;
    int np, i0;
    if (qb >= 12)     { np = 4; i0 = (15 - qb) * 4; }
    else if (qb >= 8) { np = 3; i0 = 16 + (11 - qb) * 3; }
    else              { np = 2; i0 = 28 + (7 - qb) * 2; }
    const int sidx0 = h * 38 + i0;

    const int t = threadIdx.x;
    const int r = t & 127, dv0 = (t >> 7) * 32;

    float wt[4];
    float mm = -1e30f;
    #pragma unroll
    for (int p = 0; p < 4; ++p)
        if (p < np) mm = fmaxf(mm, ml[(sidx0 + p) * 128 + r].x);
    float tot = 0.0f;
    #pragma unroll
    for (int p = 0; p < 4; ++p) {
        wt[p] = 0.0f;
        if (p < np) {
            float2 v = ml[(sidx0 + p) * 128 + r];
            wt[p] = v.y * __expf(v.x - mm);
            tot += wt[p];
        }
    }
    const float inv = 1.0f / tot;

    float accv[32];
    #pragma unroll
    for (int c = 0; c < 32; ++c) accv[c] = 0.0f;
    #pragma unroll
    for (int p = 0; p < 4; ++p) {
        if (p < np) {
            int s = sidx0 + p;
            const unsigned short* Od = (s < 384)
                ? OpA + (size_t)s * 8192
                : OpB + (size_t)(s - 384) * 8192;
            #pragma unroll
            for (int c4 = 0; c4 < 8; ++c4) {
                ushort4 v = *(const ushort4*)&Od[r * 64 + dv0 + c4 * 4];
                accv[c4 * 4 + 0] += wt[p] * bf2f(v.x);
                accv[c4 * 4 + 1] += wt[p] * bf2f(v.y);
                accv[c4 * 4 + 2] += wt[p] * bf2f(v.z);
                accv[c4 * 4 + 3] += wt[p] * bf2f(v.w);
            }
        }
    }
    const int q = qb * 128 + r;
    #pragma unroll
    for (int c4 = 0; c4 < 8; ++c4) {
        ushort4 ov;
        ov.x = f2bf(accv[c4 * 4 + 0] * inv);
        ov.y = f2bf(accv[c4 * 4 + 1] * inv);
        ov.z = f2bf(accv[c4 * 4 + 2] * inv);
        ov.w = f2bf(accv[c4 * 4 + 3] * inv);
        *(ushort4*)&attnO[(size_t)q * DMODEL + h * 64 + dv0 + c4 * 4] = ov;
    }
}

// ---------------------------------------------------------------------------
extern "C" void kernel_launch(void* const* d_in, const int* in_sizes, int n_in,
                              void* d_out, int out_size, void* d_ws, size_t ws_size,
                              hipStream_t stream)
{
    const float* x      = (const float*)d_in[0];
    const float* wq_sem = (const float*)d_in[1];
    const float* wk_sem = (const float*)d_in[2];
    const float* wq_geo = (const float*)d_in[3];
    const float* wk_geo = (const float*)d_in[4];
    const float* wv     = (const float*)d_in[5];
    const float* wo     = (const float*)d_in[6];
    const float* ksn    = (const float*)d_in[7];
    const float* kgn    = (const float*)d_in[8];
    const float* vn     = (const float*)d_in[9];
    float* out = (float*)d_out;

    // Workspace (peak 29.7 MiB):
    //  [0,        4.19M)  Xb -> attnO
    //  [4.19M,   10.49M)  WcatT -> OpA (384 partials x 16KB)
    //  [10.49M,  12.58M)  WoT
    //  [12.58M,  16.78M)  Qc  [16][2048][64]
    //  [16.78M,  21.10M)  Kc  [16][2112][64]
    //  [21.10M,  25.43M)  Vg  [16][64][2112]
    //  [25.43M,  29.10M)  OpB (224 partials x 16KB)
    //  [29.10M,  29.72M)  ml  float2 [608][128]
    char* ws = (char*)d_ws;
    unsigned short* Xb    = (unsigned short*)(ws);
    unsigned short* attnO = (unsigned short*)(ws);
    unsigned short* WcatT = (unsigned short*)(ws + 4194304);
    unsigned short* OpA   = (unsigned short*)(ws + 4194304);
    unsigned short* WoT   = (unsigned short*)(ws + 10485760);
    unsigned short* Qc    = (unsigned short*)(ws + 12582912);
    unsigned short* Kc    = (unsigned short*)(ws + 16777216);
    unsigned short* Vg    = (unsigned short*)(ws + 21102592);
    unsigned short* OpB   = (unsigned short*)(ws + 25427968);
    float2*         ml    = (float2*)(ws + 29097984);

    prep_all<<<3600, 256, 0, stream>>>(x, wq_sem, wk_sem, wq_geo, wk_geo, wv, wo,
                                       ksn, kgn, vn, Xb, WcatT, WoT, Kc, Vg);

    gemm_proj_fused<<<dim3(24, 32), 256, 0, stream>>>(Xb, WcatT, Qc, Kc, Vg);

    attn_mfma<<<656, 256, 0, stream>>>(Qc, Kc, Vg, attnO, OpA, OpB, ml);
    combine_wave<<<dim3(13, NHEAD), 256, 0, stream>>>(OpA, OpB, ml, attnO);

    gemm_out<<<dim3(8, 32), 256, 0, stream>>>(attnO, WoT, out);
}

// Round 18
// 81.265 us; speedup vs baseline: 2.3892x; 1.0104x over previous
//
#include <hip/hip_runtime.h>
#include <hip/hip_bf16.h>

typedef __hip_bfloat16 bf16;
typedef __attribute__((ext_vector_type(8))) short bf16x8;   // 8 bf16 = 4 VGPR (MFMA A/B frag)
typedef __attribute__((ext_vector_type(4))) short bf16x4;   // 4 bf16 = 8B
typedef __attribute__((ext_vector_type(4))) float f32x4;    // MFMA C/D frag

#define TSEQ   2048
#define DMODEL 1024
#define NHEAD  16
#define KST    2112   // padded key count (2049 real, zero-padded), 33*64
#define SCALE  0.17677669529663687f  // 1/sqrt(32) == sem_scale == geo_scale
#define LN1E4_16 0.5756462732485115f // ln(10000)/16

__device__ __forceinline__ unsigned short f2bf(float f) {
    union { bf16 h; unsigned short u; } x;
    x.h = __float2bfloat16(f);
    return x.u;
}
__device__ __forceinline__ float bf2f(unsigned short u) {
    return __uint_as_float(((unsigned int)u) << 16);
}

__device__ __forceinline__ void gload_lds16(const void* g, void* l) {
    __builtin_amdgcn_global_load_lds(
        (const __attribute__((address_space(1))) void*)g,
        (__attribute__((address_space(3))) void*)l, 16, 0, 0);
}

// ---------------------------------------------------------------------------
// prep_all: one launch for X convert (bx<2048), 6 weight transposes
// (bx in [2048,3584)), and null/pad init (bx >= 3584).
// ---------------------------------------------------------------------------
__global__ __launch_bounds__(256) void prep_all(
    const float* __restrict__ X,
    const float* __restrict__ wqs, const float* __restrict__ wks,
    const float* __restrict__ wqg, const float* __restrict__ wkg,
    const float* __restrict__ wv,  const float* __restrict__ wo,
    const float* __restrict__ ksn, const float* __restrict__ kgn,
    const float* __restrict__ vn,
    unsigned short* __restrict__ Xb,
    unsigned short* __restrict__ WcatT, unsigned short* __restrict__ WoT,
    unsigned short* __restrict__ Kc, unsigned short* __restrict__ Vg)
{
    __shared__ float T[64][65];
    const int bx = blockIdx.x;
    const int tid = threadIdx.x;
    if (bx < 2048) {
        int i = (bx * 256 + tid) * 4;
        float4 v = *(const float4*)(X + i);
        ushort4 o;
        o.x = f2bf(v.x); o.y = f2bf(v.y); o.z = f2bf(v.z); o.w = f2bf(v.w);
        *(ushort4*)(Xb + i) = o;
    } else if (bx < 3584) {
        const int idx = bx - 2048;
        const int z = idx >> 8, rem = idx & 255;
        const int cx = rem & 15, ry = rem >> 4;
        const float* src; unsigned short* dst; int C;
        switch (z) {
            case 0: src = wqs; dst = WcatT;               C = 512;  break;
            case 1: src = wks; dst = WcatT + 512  * 1024; C = 512;  break;
            case 2: src = wqg; dst = WcatT + 1024 * 1024; C = 512;  break;
            case 3: src = wkg; dst = WcatT + 1536 * 1024; C = 512;  break;
            case 4: src = wv;  dst = WcatT + 2048 * 1024; C = 1024; break;
            default: src = wo; dst = WoT;                 C = 1024; break;
        }
        const int c0 = cx * 64;
        if (c0 >= C) return;
        const int r0 = ry * 64;
        #pragma unroll
        for (int i = 0; i < 16; ++i) {
            int id2 = tid + 256 * i;
            int r = id2 >> 6, c = id2 & 63;
            T[r][c] = src[(size_t)(r0 + r) * C + c0 + c];
        }
        __syncthreads();
        #pragma unroll
        for (int i = 0; i < 16; ++i) {
            int id2 = tid + 256 * i;
            int cc = id2 >> 6, rr = id2 & 63;
            dst[(size_t)(c0 + cc) * 1024 + r0 + rr] = f2bf(T[rr][cc]);
        }
    } else {
        const int h = bx - 3584;
        const int d = tid & 63, g = tid >> 6;
        if (g == 0)
            Kc[((size_t)h * KST + 0) * 64 + d] =
                f2bf(d < 32 ? ksn[h * 32 + d] : kgn[h * 32 + d - 32]);
        if (g == 1)
            Vg[((size_t)h * 64 + d) * KST + 0] = f2bf(vn[h * 64 + d]);
        for (int fk = 2049 + g; fk < KST; fk += 4) {
            Kc[((size_t)h * KST + fk) * 64 + d] = 0;
            Vg[((size_t)h * 64 + d) * KST + fk] = 0;
        }
    }
}

// ---------------------------------------------------------------------------
// Fused projection GEMM: 64x128 tile, BK=64, single-buffer swizzled LDS.
// Epilogue writes attention layouts (Qc pre-scaled, RoPE fused).
// ---------------------------------------------------------------------------
__global__ __launch_bounds__(256) void gemm_proj_fused(
    const unsigned short* __restrict__ A,   // Xb [2048][1024]
    const unsigned short* __restrict__ Bt,  // WcatT [3072][1024]
    unsigned short* __restrict__ Qc,
    unsigned short* __restrict__ Kc,
    unsigned short* __restrict__ Vg)
{
    __shared__ __align__(16) unsigned short Abuf[64 * 64];    //  8 KB
    __shared__ __align__(16) unsigned short Bbuf[128 * 64];   // 16 KB
    const int n0 = blockIdx.x * 128, m0 = blockIdx.y * 64;
    const int tid = threadIdx.x, l = tid & 63, wv = tid >> 6;
    const int wr = wv >> 1, wc = wv & 1;      // wave tile: 32 rows x 64 cols
    const int lr = l & 15, lg = l >> 4;

    f32x4 acc[2][4];
    #pragma unroll
    for (int i = 0; i < 2; ++i)
        #pragma unroll
        for (int j = 0; j < 4; ++j) acc[i][j] = (f32x4){0.f, 0.f, 0.f, 0.f};

    for (int k0 = 0; k0 < 1024; k0 += 64) {
        #pragma unroll
        for (int i = 0; i < 2; ++i) {              // A: 2 chunks/thread
            int c = wv * 128 + i * 64 + l;
            int row = c >> 3, sseg = (c & 7) ^ (row & 7);
            gload_lds16(A + (size_t)(m0 + row) * 1024 + k0 + sseg * 8,
                        &Abuf[(wv * 128 + i * 64) * 8]);
        }
        #pragma unroll
        for (int i = 0; i < 4; ++i) {              // B: 4 chunks/thread
            int c = wv * 256 + i * 64 + l;
            int row = c >> 3, sseg = (c & 7) ^ (row & 7);
            gload_lds16(Bt + (size_t)(n0 + row) * 1024 + k0 + sseg * 8,
                        &Bbuf[(wv * 256 + i * 64) * 8]);
        }
        __syncthreads();
        #pragma unroll
        for (int ks = 0; ks < 2; ++ks) {
            bf16x8 af[2], bfv[4];
            #pragma unroll
            for (int mf = 0; mf < 2; ++mf) {
                int rr = wr * 32 + mf * 16 + lr;
                int seg = (ks * 4 + lg) ^ (rr & 7);
                af[mf] = *(const bf16x8*)&Abuf[rr * 64 + seg * 8];
            }
            #pragma unroll
            for (int nf = 0; nf < 4; ++nf) {
                int rr = wc * 64 + nf * 16 + lr;
                int seg = (ks * 4 + lg) ^ (rr & 7);
                bfv[nf] = *(const bf16x8*)&Bbuf[rr * 64 + seg * 8];
            }
            #pragma unroll
            for (int mf = 0; mf < 2; ++mf)
                #pragma unroll
                for (int nf = 0; nf < 4; ++nf)
                    acc[mf][nf] = __builtin_amdgcn_mfma_f32_16x16x32_bf16(
                        af[mf], bfv[nf], acc[mf][nf], 0, 0, 0);
        }
        __syncthreads();
    }

    const int sec = n0 >> 9;   // 0 qs | 1 ks | 2 qg | 3 kg | 4,5 v
    if (sec <= 1) {
        unsigned short* dst = (sec == 0) ? Qc : Kc;
        const int tstr  = (sec == 0) ? TSEQ : KST;
        const int fkoff = (sec == 0) ? 0 : 1;
        const float sc  = (sec == 0) ? SCALE : 1.0f;
        #pragma unroll
        for (int mf = 0; mf < 2; ++mf)
            #pragma unroll
            for (int nf = 0; nf < 4; ++nf) {
                int col = (n0 & 511) + wc * 64 + nf * 16 + lr;
                int h = col >> 5, d = col & 31;
                #pragma unroll
                for (int reg = 0; reg < 4; ++reg) {
                    int q = m0 + wr * 32 + mf * 16 + lg * 4 + reg;
                    dst[((size_t)h * tstr + q + fkoff) * 64 + d] =
                        f2bf(acc[mf][nf][reg] * sc);
                }
            }
    } else if (sec <= 3) {
        unsigned short* dst = (sec == 2) ? Qc : Kc;
        const int tstr  = (sec == 2) ? TSEQ : KST;
        const int fkoff = (sec == 2) ? 0 : 1;
        const float sc  = (sec == 2) ? SCALE : 1.0f;
        const float invf = __expf(-(float)lr * LN1E4_16);
        #pragma unroll
        for (int mf = 0; mf < 2; ++mf)
            #pragma unroll
            for (int reg = 0; reg < 4; ++reg) {
                int q = m0 + wr * 32 + mf * 16 + lg * 4 + reg;
                float s, c;
                __sincosf((float)q * invf, &s, &c);
                #pragma unroll
                for (int nfp = 0; nfp < 2; ++nfp) {
                    int nf0 = nfp * 2;
                    int colbase = (n0 & 511) + wc * 64 + nf0 * 16;
                    int h = colbase >> 5;
                    float x1 = acc[mf][nf0][reg], x2 = acc[mf][nf0 + 1][reg];
                    size_t base = ((size_t)h * tstr + q + fkoff) * 64 + 32;
                    dst[base + lr]      = f2bf((x1 * c - x2 * s) * sc);
                    dst[base + lr + 16] = f2bf((x2 * c + x1 * s) * sc);
                }
            }
    } else {
        #pragma unroll
        for (int nf = 0; nf < 4; ++nf) {
            int colr = (n0 - 2048) + wc * 64 + nf * 16 + lr;
            int h = colr >> 6, dv = colr & 63;
            size_t rowbase = ((size_t)h * 64 + dv) * KST;
            #pragma unroll
            for (int mf = 0; mf < 2; ++mf)
                #pragma unroll
                for (int reg = 0; reg < 4; ++reg) {
                    int q = m0 + wr * 32 + mf * 16 + lg * 4 + reg;
                    Vg[rowbase + q + 1] = f2bf(acc[mf][nf][reg]);
                }
        }
    }
}

// ---------------------------------------------------------------------------
// Output GEMM: 64x128 tile, BK=64, single-buffer swizzled LDS.
// ---------------------------------------------------------------------------
__global__ __launch_bounds__(256) void gemm_out(const unsigned short* __restrict__ A,
                                                const unsigned short* __restrict__ Bt,
                                                float* __restrict__ C)
{
    __shared__ __align__(16) unsigned short Abuf[64 * 64];
    __shared__ __align__(16) unsigned short Bbuf[128 * 64];
    const int n0 = blockIdx.x * 128, m0 = blockIdx.y * 64;
    const int tid = threadIdx.x, l = tid & 63, wv = tid >> 6;
    const int wr = wv >> 1, wc = wv & 1;
    const int lr = l & 15, lg = l >> 4;

    f32x4 acc[2][4];
    #pragma unroll
    for (int i = 0; i < 2; ++i)
        #pragma unroll
        for (int j = 0; j < 4; ++j) acc[i][j] = (f32x4){0.f, 0.f, 0.f, 0.f};

    for (int k0 = 0; k0 < 1024; k0 += 64) {
        #pragma unroll
        for (int i = 0; i < 2; ++i) {
            int c = wv * 128 + i * 64 + l;
            int row = c >> 3, sseg = (c & 7) ^ (row & 7);
            gload_lds16(A + (size_t)(m0 + row) * 1024 + k0 + sseg * 8,
                        &Abuf[(wv * 128 + i * 64) * 8]);
        }
        #pragma unroll
        for (int i = 0; i < 4; ++i) {
            int c = wv * 256 + i * 64 + l;
            int row = c >> 3, sseg = (c & 7) ^ (row & 7);
            gload_lds16(Bt + (size_t)(n0 + row) * 1024 + k0 + sseg * 8,
                        &Bbuf[(wv * 256 + i * 64) * 8]);
        }
        __syncthreads();
        #pragma unroll
        for (int ks = 0; ks < 2; ++ks) {
            bf16x8 af[2], bfv[4];
            #pragma unroll
            for (int mf = 0; mf < 2; ++mf) {
                int rr = wr * 32 + mf * 16 + lr;
                int seg = (ks * 4 + lg) ^ (rr & 7);
                af[mf] = *(const bf16x8*)&Abuf[rr * 64 + seg * 8];
            }
            #pragma unroll
            for (int nf = 0; nf < 4; ++nf) {
                int rr = wc * 64 + nf * 16 + lr;
                int seg = (ks * 4 + lg) ^ (rr & 7);
                bfv[nf] = *(const bf16x8*)&Bbuf[rr * 64 + seg * 8];
            }
            #pragma unroll
            for (int mf = 0; mf < 2; ++mf)
                #pragma unroll
                for (int nf = 0; nf < 4; ++nf)
                    acc[mf][nf] = __builtin_amdgcn_mfma_f32_16x16x32_bf16(
                        af[mf], bfv[nf], acc[mf][nf], 0, 0, 0);
        }
        __syncthreads();
    }
    #pragma unroll
    for (int mf = 0; mf < 2; ++mf)
        #pragma unroll
        for (int nf = 0; nf < 4; ++nf)
            #pragma unroll
            for (int reg = 0; reg < 4; ++reg) {
                int row = m0 + wr * 32 + mf * 16 + lg * 4 + reg;
                int col = n0 + wc * 64 + nf * 16 + lr;
                C[(size_t)row * DMODEL + col] = acc[mf][nf][reg];
            }
}

// ---------------------------------------------------------------------------
// MFMA flash attention, QBLK=128, depth-2 pipeline + r17 phase reschedule +
// DEFERRED row-sum reduce: ll[] holds per-lane partials (alpha rescale is
// row-uniform so partials stay consistent); the 2-stage shfl reduce runs
// ONCE in the epilogue instead of every iteration.
// ---------------------------------------------------------------------------
__global__ __launch_bounds__(256, 3) void attn_mfma(
    const unsigned short* __restrict__ Qc,
    const unsigned short* __restrict__ Kc,
    const unsigned short* __restrict__ Vg,
    unsigned short* __restrict__ attnO,
    unsigned short* __restrict__ OpA,
    unsigned short* __restrict__ OpB,
    float2* __restrict__ ml)
{
    __shared__ __align__(16) unsigned short KsL[3][64 * 64];   // 24 KB
    __shared__ __align__(16) unsigned short VsL[2][64 * 64];   // 16 KB
    __shared__ __align__(16) unsigned short Ps[64 * 64];       //  8 KB

    const int ib = blockIdx.x;          // 0..655
    const int hp = ib & 7;
    const int j  = ib >> 3;             // 0..81
    const int h  = hp * 2 + (j & 1);
    const int item = j >> 1;            // 0..40, heavy-first

    int qb, part, np;
    {
        int i = item;
        if (i < 16)      { np = 4; qb = 15 - (i >> 2); part = i & 3; }
        else if (i < 28) { int jj = i - 16; np = 3; qb = 11 - jj / 3; part = jj % 3; }
        else if (i < 38) { int jj = i - 28; np = 2; qb = 7 - (jj >> 1); part = jj & 1; }
        else             { np = 1; qb = 2 - (i - 38); part = 0; }
    }
    const int nt = 2 * qb + 3;
    const int bsz = nt / np, rem = nt % np;
    const int t0 = part * bsz + (part < rem ? part : rem);
    const int t1 = t0 + bsz + (part < rem ? 1 : 0);   // t1-t0 >= 3 always

    const int q0 = qb * 128;
    const int tid = threadIdx.x, l = tid & 63, w = tid >> 6;
    const int lr = l & 15, lg = l >> 4;

    bf16x8 qa[2][2];
    #pragma unroll
    for (int rg = 0; rg < 2; ++rg) {
        int qr = q0 + w * 32 + rg * 16 + lr;
        qa[rg][0] = *(const bf16x8*)&Qc[((size_t)h * TSEQ + qr) * 64 + lg * 8];
        qa[rg][1] = *(const bf16x8*)&Qc[((size_t)h * TSEQ + qr) * 64 + 32 + lg * 8];
    }

    const int sc8 = (((l & 7) ^ ((l >> 3) & 7))) * 8;
    const int r0s = (w * 2 + 0) * 8 + (l >> 3);
    const int r1s = (w * 2 + 1) * 8 + (l >> 3);
    const unsigned short* Kh = Kc + (((size_t)h * KST) << 6);
    const unsigned short* Vh = Vg + (size_t)h * 64 * KST;

#define STAGE_K(bufi, fk0_) do {                                               \
        gload_lds16(Kh + (((size_t)((fk0_) + r0s)) << 6) + sc8,                \
                    &KsL[bufi][(w * 2 + 0) * 512]);                            \
        gload_lds16(Kh + (((size_t)((fk0_) + r1s)) << 6) + sc8,                \
                    &KsL[bufi][(w * 2 + 1) * 512]);                            \
    } while (0)
#define STAGE_V(bufi, fk0_) do {                                               \
        gload_lds16(Vh + (size_t)r0s * KST + (fk0_) + sc8,                     \
                    &VsL[bufi][(w * 2 + 0) * 512]);                            \
        gload_lds16(Vh + (size_t)r1s * KST + (fk0_) + sc8,                     \
                    &VsL[bufi][(w * 2 + 1) * 512]);                            \
    } while (0)

    f32x4 o[2][4];
    #pragma unroll
    for (int rg = 0; rg < 2; ++rg)
        #pragma unroll
        for (int i = 0; i < 4; ++i) o[rg][i] = (f32x4){0.f, 0.f, 0.f, 0.f};
    float m[2]  = {-1e30f, -1e30f};
    float ll[2] = {0.f, 0.f};        // PER-LANE partial row sums

    STAGE_K(t0 % 3, t0 * 64);
    STAGE_V(t0 & 1, t0 * 64);
    STAGE_K((t0 + 1) % 3, (t0 + 1) * 64);
    asm volatile("s_waitcnt vmcnt(2)" ::: "memory");
    __builtin_amdgcn_s_barrier();

    for (int kb = t0; kb < t1; ++kb) {
        const int fk0 = kb * 64;
        const unsigned short* Ksb = &KsL[kb % 3][0];
        const unsigned short* Vsb = &VsL[kb & 1][0];
        const bool moreV = (kb + 1 < t1);
        const bool moreK = (kb + 2 < t1);
        if (moreV) STAGE_V((kb + 1) & 1, fk0 + 64);    // V first (drained at bottom)
        if (moreK) STAGE_K((kb + 2) % 3, fk0 + 128);   // K second (stays in flight)

        bf16x8 vb[2][4];
        #pragma unroll
        for (int ks = 0; ks < 2; ++ks)
            #pragma unroll
            for (int nf = 0; nf < 4; ++nf) {
                int dv = nf * 16 + lr;
                vb[ks][nf] = *(const bf16x8*)
                    &Vsb[dv * 64 + ((lg * 8 + ks * 32) ^ ((dv & 7) << 3))];
            }

        f32x4 sa[2][4];
        #pragma unroll
        for (int rg = 0; rg < 2; ++rg)
            #pragma unroll
            for (int i = 0; i < 4; ++i) sa[rg][i] = (f32x4){0.f, 0.f, 0.f, 0.f};
        #pragma unroll
        for (int ks = 0; ks < 2; ++ks) {
            int dd = lg * 8 + ks * 32;
            #pragma unroll
            for (int nf = 0; nf < 4; ++nf) {
                int kkc = nf * 16 + lr;
                bf16x8 kbf = *(const bf16x8*)&Ksb[kkc * 64 + (dd ^ ((kkc & 7) << 3))];
                sa[0][nf] = __builtin_amdgcn_mfma_f32_16x16x32_bf16(kbf, qa[0][ks], sa[0][nf], 0, 0, 0);
                sa[1][nf] = __builtin_amdgcn_mfma_f32_16x16x32_bf16(kbf, qa[1][ks], sa[1][nf], 0, 0, 0);
            }
        }

        const bool needmask = (fk0 + 62 > q0 + w * 32);
        const int pr = w * 16 + lr;
        const int psw = (pr & 7) << 3;

#define SOFTMAX_RG(RG) do {                                                    \
        const int q = q0 + w * 32 + (RG) * 16 + lr;                            \
        float mt = -1e30f;                                                     \
        if (needmask) {                                                        \
            _Pragma("unroll")                                                  \
            for (int nf = 0; nf < 4; ++nf)                                     \
                _Pragma("unroll")                                              \
                for (int reg = 0; reg < 4; ++reg) {                            \
                    int fk = fk0 + nf * 16 + lg * 4 + reg;                     \
                    float val = (fk <= q + 1) ? sa[RG][nf][reg] : -1e9f;       \
                    sa[RG][nf][reg] = val;                                     \
                    mt = fmaxf(mt, val);                                       \
                }                                                              \
        } else {                                                               \
            _Pragma("unroll")                                                  \
            for (int nf = 0; nf < 4; ++nf)                                     \
                _Pragma("unroll")                                              \
                for (int reg = 0; reg < 4; ++reg)                              \
                    mt = fmaxf(mt, sa[RG][nf][reg]);                           \
        }                                                                      \
        mt = fmaxf(mt, __shfl_xor(mt, 16, 64));                                \
        mt = fmaxf(mt, __shfl_xor(mt, 32, 64));                                \
        if (__any(mt > m[RG] + 8.0f)) {                                        \
            float mn = fmaxf(m[RG], mt);                                       \
            float alpha = __expf(m[RG] - mn);                                  \
            m[RG] = mn;                                                        \
            ll[RG] *= alpha;                                                   \
            _Pragma("unroll")                                                  \
            for (int nf = 0; nf < 4; ++nf)                                     \
                _Pragma("unroll")                                              \
                for (int reg = 0; reg < 4; ++reg)                              \
                    o[RG][nf][reg] *= alpha;                                   \
        }                                                                      \
        float rs = 0.0f;                                                       \
        _Pragma("unroll")                                                      \
        for (int nf = 0; nf < 4; ++nf)                                         \
            _Pragma("unroll")                                                  \
            for (int reg = 0; reg < 4; ++reg) {                                \
                float p = __expf(sa[RG][nf][reg] - m[RG]);                     \
                sa[RG][nf][reg] = p;                                           \
                rs += p;                                                       \
            }                                                                  \
        ll[RG] += rs;   /* per-lane partial; reduced once in epilogue */       \
    } while (0)

#define WRITE_PS(RG) do {                                                      \
        _Pragma("unroll")                                                      \
        for (int nf = 0; nf < 4; ++nf) {                                       \
            bf16x4 pk;                                                         \
            pk[0] = f2bf(sa[RG][nf][0]); pk[1] = f2bf(sa[RG][nf][1]);          \
            pk[2] = f2bf(sa[RG][nf][2]); pk[3] = f2bf(sa[RG][nf][3]);          \
            int kk0 = nf * 16 + lg * 4;                                        \
            *(bf16x4*)&Ps[pr * 64 + (kk0 ^ psw)] = pk;                         \
        }                                                                      \
    } while (0)

#define PV_RG(RG) do {                                                         \
        _Pragma("unroll")                                                      \
        for (int ks = 0; ks < 2; ++ks) {                                       \
            int kk0 = lg * 8 + ks * 32;                                        \
            bf16x8 pa = *(const bf16x8*)&Ps[pr * 64 + (kk0 ^ psw)];            \
            _Pragma("unroll")                                                  \
            for (int nf = 0; nf < 4; ++nf)                                     \
                o[RG][nf] = __builtin_amdgcn_mfma_f32_16x16x32_bf16(           \
                    vb[ks][nf], pa, o[RG][nf], 0, 0, 0);                       \
        }                                                                      \
    } while (0)

        SOFTMAX_RG(0);
        WRITE_PS(0);
        SOFTMAX_RG(1);     // VALU work hides rg0's Ps write->read DS latency
        PV_RG(0);
        WRITE_PS(1);       // same-wave DS order: after PV_RG(0)'s reads
        PV_RG(1);

#undef SOFTMAX_RG
#undef WRITE_PS
#undef PV_RG

        if (moreK) { asm volatile("s_waitcnt vmcnt(2)" ::: "memory"); }
        else       { asm volatile("s_waitcnt vmcnt(0)" ::: "memory"); }
        __builtin_amdgcn_s_barrier();
    }
#undef STAGE_K
#undef STAGE_V

    const int sidx = h * 38 + item;
    unsigned short* Od = (np == 1) ? 0
        : ((sidx < 384) ? OpA + (size_t)sidx * 8192
                        : OpB + (size_t)(sidx - 384) * 8192);
    #pragma unroll
    for (int rg = 0; rg < 2; ++rg) {
        // deferred row-sum reduce (once per block)
        float lt = ll[rg];
        lt += __shfl_xor(lt, 16, 64);
        lt += __shfl_xor(lt, 32, 64);
        const float inv = 1.0f / lt;
        const int q = q0 + w * 32 + rg * 16 + lr;
        if (np == 1) {
            #pragma unroll
            for (int nf = 0; nf < 4; ++nf) {
                ushort4 ov;
                ov.x = f2bf(o[rg][nf][0] * inv); ov.y = f2bf(o[rg][nf][1] * inv);
                ov.z = f2bf(o[rg][nf][2] * inv); ov.w = f2bf(o[rg][nf][3] * inv);
                *(ushort4*)&attnO[(size_t)q * DMODEL + h * 64 + nf * 16 + lg * 4] = ov;
            }
        } else {
            const int r = w * 32 + rg * 16 + lr;
            #pragma unroll
            for (int nf = 0; nf < 4; ++nf) {
                ushort4 ov;
                ov.x = f2bf(o[rg][nf][0] * inv); ov.y = f2bf(o[rg][nf][1] * inv);
                ov.z = f2bf(o[rg][nf][2] * inv); ov.w = f2bf(o[rg][nf][3] * inv);
                *(ushort4*)&Od[r * 64 + nf * 16 + lg * 4] = ov;
            }
            if (lg == 0)
                ml[sidx * 128 + r] = make_float2(m[rg], lt);
        }
    }
}

// ---------------------------------------------------------------------------
// Combine split partials: one block per (h, qb in [3,16)). np in {2,3,4}.
// ---------------------------------------------------------------------------
__global__ __launch_bounds__(256) void combine_wave(
    const unsigned short* __restrict__ OpA,
    const unsigned short* __restrict__ OpB,
    const float2* __restrict__ ml,
    unsigned short* __restrict__ attnO)
{
    const int qb = 3 + blockIdx.x;   // 3..15
    const int h  = blockIdx.y;
    int np, i0;
    if (qb >= 12)     { np = 4; i0 = (15 - qb) * 4; }
    else if (qb >= 8) { np = 3; i0 = 16 + (11 - qb) * 3; }
    else              { np = 2; i0 = 28 + (7 - qb) * 2; }
    const int sidx0 = h * 38 + i0;

    const int t = threadIdx.x;
    const int r = t & 127, dv0 = (t >> 7) * 32;

    float wt[4];
    float mm = -1e30f;
    #pragma unroll
    for (int p = 0; p < 4; ++p)
        if (p < np) mm = fmaxf(mm, ml[(sidx0 + p) * 128 + r].x);
    float tot = 0.0f;
    #pragma unroll
    for (int p = 0; p < 4; ++p) {
        wt[p] = 0.0f;
        if (p < np) {
            float2 v = ml[(sidx0 + p) * 128 + r];
            wt[p] = v.y * __expf(v.x - mm);
            tot += wt[p];
        }
    }
    const float inv = 1.0f / tot;

    float accv[32];
    #pragma unroll
    for (int c = 0; c < 32; ++c) accv[c] = 0.0f;
    #pragma unroll
    for (int p = 0; p < 4; ++p) {
        if (p < np) {
            int s = sidx0 + p;
            const unsigned short* Od = (s < 384)
                ? OpA + (size_t)s * 8192
                : OpB + (size_t)(s - 384) * 8192;
            #pragma unroll
            for (int c4 = 0; c4 < 8; ++c4) {
                ushort4 v = *(const ushort4*)&Od[r * 64 + dv0 + c4 * 4];
                accv[c4 * 4 + 0] += wt[p] * bf2f(v.x);
                accv[c4 * 4 + 1] += wt[p] * bf2f(v.y);
                accv[c4 * 4 + 2] += wt[p] * bf2f(v.z);
                accv[c4 * 4 + 3] += wt[p] * bf2f(v.w);
            }
        }
    }
    const int q = qb * 128 + r;
    #pragma unroll
    for (int c4 = 0; c4 < 8; ++c4) {
        ushort4 ov;
        ov.x = f2bf(accv[c4 * 4 + 0] * inv);
        ov.y = f2bf(accv[c4 * 4 + 1] * inv);
        ov.z = f2bf(accv[c4 * 4 + 2] * inv);
        ov.w = f2bf(accv[c4 * 4 + 3] * inv);
        *(ushort4*)&attnO[(size_t)q * DMODEL + h * 64 + dv0 + c4 * 4] = ov;
    }
}

// ---------------------------------------------------------------------------
extern "C" void kernel_launch(void* const* d_in, const int* in_sizes, int n_in,
                              void* d_out, int out_size, void* d_ws, size_t ws_size,
                              hipStream_t stream)
{
    const float* x      = (const float*)d_in[0];
    const float* wq_sem = (const float*)d_in[1];
    const float* wk_sem = (const float*)d_in[2];
    const float* wq_geo = (const float*)d_in[3];
    const float* wk_geo = (const float*)d_in[4];
    const float* wv     = (const float*)d_in[5];
    const float* wo     = (const float*)d_in[6];
    const float* ksn    = (const float*)d_in[7];
    const float* kgn    = (const float*)d_in[8];
    const float* vn     = (const float*)d_in[9];
    float* out = (float*)d_out;

    // Workspace (peak 29.7 MiB):
    //  [0,        4.19M)  Xb -> attnO
    //  [4.19M,   10.49M)  WcatT -> OpA (384 partials x 16KB)
    //  [10.49M,  12.58M)  WoT
    //  [12.58M,  16.78M)  Qc  [16][2048][64]
    //  [16.78M,  21.10M)  Kc  [16][2112][64]
    //  [21.10M,  25.43M)  Vg  [16][64][2112]
    //  [25.43M,  29.10M)  OpB (224 partials x 16KB)
    //  [29.10M,  29.72M)  ml  float2 [608][128]
    char* ws = (char*)d_ws;
    unsigned short* Xb    = (unsigned short*)(ws);
    unsigned short* attnO = (unsigned short*)(ws);
    unsigned short* WcatT = (unsigned short*)(ws + 4194304);
    unsigned short* OpA   = (unsigned short*)(ws + 4194304);
    unsigned short* WoT   = (unsigned short*)(ws + 10485760);
    unsigned short* Qc    = (unsigned short*)(ws + 12582912);
    unsigned short* Kc    = (unsigned short*)(ws + 16777216);
    unsigned short* Vg    = (unsigned short*)(ws + 21102592);
    unsigned short* OpB   = (unsigned short*)(ws + 25427968);
    float2*         ml    = (float2*)(ws + 29097984);

    prep_all<<<3600, 256, 0, stream>>>(x, wq_sem, wk_sem, wq_geo, wk_geo, wv, wo,
                                       ksn, kgn, vn, Xb, WcatT, WoT, Kc, Vg);

    gemm_proj_fused<<<dim3(24, 32), 256, 0, stream>>>(Xb, WcatT, Qc, Kc, Vg);

    attn_mfma<<<656, 256, 0, stream>>>(Qc, Kc, Vg, attnO, OpA, OpB, ml);
    combine_wave<<<dim3(13, NHEAD), 256, 0, stream>>>(OpA, OpB, ml, attnO);

    gemm_out<<<dim3(8, 32), 256, 0, stream>>>(attnO, WoT, out);
}